// Round 2
// baseline (418.187 us; speedup 1.0000x reference)
//
#include <hip/hip_runtime.h>
#include <climits>
#include <cmath>

// YOLOv9 loss forward.  B=32 T=64 A=8400 C=80.
// Pipeline: k_topk (per (b,t) row top-10, grid-mask-compacted) -> k_assign
// (per batch dedup + matched-anchor loss terms) -> k_bce (softplus sum over
// predict_cls) -> k_final (combine).  All reductions fixed-order.

#define NB 32
#define NT 64
#define NA 8400
#define NC 80
#define KTOP 10
#define CAP 4096
#define EPSF 1e-7f
#define INV_PI2 0.40528473456935108577f  // 4/pi^2

__device__ __forceinline__ float atan_wh(float x1, float y1, float x2, float y2) {
  return atanf((x2 - x1) / (y2 - y1 + EPSF));
}

__device__ __forceinline__ float ciou_pair(
    float ax1, float ay1, float ax2, float ay2, float atA,
    float bx1, float by1, float bx2, float by2, float atB)
{
  float xi1 = fmaxf(ax1, bx1), yi1 = fmaxf(ay1, by1);
  float xi2 = fminf(ax2, bx2), yi2 = fminf(ay2, by2);
  float inter = fmaxf(xi2 - xi1, 0.f) * fmaxf(yi2 - yi1, 0.f);
  float a1 = (ax2 - ax1) * (ay2 - ay1);
  float a2 = (bx2 - bx1) * (by2 - by1);
  float iou = inter / (a1 + a2 - inter + EPSF);
  float dcx = (ax2 + ax1) * 0.5f - (bx2 + bx1) * 0.5f;
  float dcy = (ay2 + ay1) * 0.5f - (by2 + by1) * 0.5f;
  float cent = dcx * dcx + dcy * dcy;
  float cw = fmaxf(ax2, bx2) - fminf(ax1, bx1);
  float ch = fmaxf(ay2, by2) - fminf(ay1, by1);
  float diag = cw * cw + ch * ch + EPSF;
  float dv = atA - atB;
  float v = INV_PI2 * dv * dv;
  float alpha = v / (v - iou + 1.f + EPSF);
  return iou - cent / diag - alpha * v;
}

__device__ __forceinline__ float softplus_f(float x) {
  return fmaxf(x, 0.f) + log1pf(expf(-fabsf(x)));
}

// ---- K1: per (b,t) row: compact grid-passing anchors, select top-10 ------
__global__ __launch_bounds__(256) void k_topk(
    const float* __restrict__ target,   // [B,T,5]
    const float* __restrict__ pcls,     // [B,A,C]
    const float* __restrict__ pbox,     // [B,A,4]
    const float* __restrict__ anchors,  // [A,2]
    float* __restrict__ top_val, int* __restrict__ top_idx,
    float* __restrict__ top_iou)
{
  int row = blockIdx.x;            // b*NT + t
  int b = row >> 6;
  const float* tg = target + (size_t)row * 5;
  float tcf = tg[0];
  float x1 = tg[1], y1 = tg[2], x2 = tg[3], y2 = tg[4];
  int tc = (int)tcf; tc = tc < 0 ? 0 : (tc > NC - 1 ? NC - 1 : tc);
  float atan_t = atan_wh(x1, y1, x2, y2);

  __shared__ int s_n;
  __shared__ float s_val[CAP];
  __shared__ int s_idx[CAP];
  __shared__ float r_val[256];
  __shared__ int r_idx[256];
  __shared__ float w_val[KTOP];
  __shared__ int w_idx[KTOP];
  if (threadIdx.x == 0) s_n = 0;
  __syncthreads();

  const float* pb_b = pbox + (size_t)b * NA * 4;
  const float* pc_b = pcls + (size_t)b * NA * NC;
  const float2* an2 = (const float2*)anchors;

  for (int a = threadIdx.x; a < NA; a += 256) {
    float2 an = an2[a];
    if (x1 < an.x && an.x < x2 && y1 < an.y && an.y < y2) {
      float bx1 = pb_b[4 * a], by1 = pb_b[4 * a + 1];
      float bx2 = pb_b[4 * a + 2], by2 = pb_b[4 * a + 3];
      float c = ciou_pair(x1, y1, x2, y2, atan_t, bx1, by1, bx2, by2,
                          atan_wh(bx1, by1, bx2, by2));
      float io = fminf(fmaxf(c, 0.f), 1.f);
      float i2 = io * io;
      float i6 = i2 * i2 * i2;
      float s = pc_b[(size_t)a * NC + tc];
      float sig = 1.f / (1.f + expf(-s));
      float tm = i6 * sqrtf(sig);
      int slot = atomicAdd(&s_n, 1);
      if (slot < CAP) { s_val[slot] = tm; s_idx[slot] = a; }
    }
  }
  __syncthreads();
  int n = s_n; if (n > CAP) n = CAP;

  // iterative top-10: (value desc, index asc) — matches lax.top_k tie-break
  for (int k = 0; k < KTOP; k++) {
    float bv = -1.f; int bi = INT_MAX;
    for (int e = threadIdx.x; e < n; e += 256) {
      float v = s_val[e]; int i = s_idx[e];
      if (v > bv || (v == bv && i < bi)) { bv = v; bi = i; }
    }
    r_val[threadIdx.x] = bv; r_idx[threadIdx.x] = bi;
    __syncthreads();
    for (int off = 128; off > 0; off >>= 1) {
      if (threadIdx.x < off) {
        float v = r_val[threadIdx.x + off]; int i = r_idx[threadIdx.x + off];
        if (v > r_val[threadIdx.x] ||
            (v == r_val[threadIdx.x] && i < r_idx[threadIdx.x])) {
          r_val[threadIdx.x] = v; r_idx[threadIdx.x] = i;
        }
      }
      __syncthreads();
    }
    if (threadIdx.x == 0) { w_val[k] = r_val[0]; w_idx[k] = r_idx[0]; }
    __syncthreads();
    int win = r_idx[0];
    if (win != INT_MAX) {
      for (int e = threadIdx.x; e < n; e += 256)
        if (s_idx[e] == win) s_val[e] = -1.f;
    }
    __syncthreads();
  }

  // write winners; recompute clipped ciou for each (10 per block, trivial)
  if (threadIdx.x < KTOP) {
    int k = threadIdx.x;
    int ai = w_idx[k]; float v = w_val[k];
    float io = 0.f;
    if (ai != INT_MAX && v > 0.f) {
      float bx1 = pb_b[4 * ai], by1 = pb_b[4 * ai + 1];
      float bx2 = pb_b[4 * ai + 2], by2 = pb_b[4 * ai + 3];
      float c = ciou_pair(x1, y1, x2, y2, atan_t, bx1, by1, bx2, by2,
                          atan_wh(bx1, by1, bx2, by2));
      io = fminf(fmaxf(c, 0.f), 1.f);
    } else { ai = -1; v = 0.f; }
    size_t o = (size_t)row * KTOP + k;
    top_val[o] = v; top_idx[o] = ai; top_iou[o] = io;
  }
}

// ---- K2: per-batch dedup + normalize + matched-anchor loss terms ---------
__global__ __launch_bounds__(256) void k_assign(
    const float* __restrict__ target, const float* __restrict__ pcls,
    const float* __restrict__ pbox, const float* __restrict__ anchors,
    const float* __restrict__ top_val, const int* __restrict__ top_idx,
    const float* __restrict__ top_iou,
    double* __restrict__ part /* [NB][3] */)
{
  int b = blockIdx.x;
  int tid = threadIdx.x;
  const int NE = NT * KTOP;  // 640 candidate entries

  __shared__ float e_val[NE]; __shared__ int e_idx[NE]; __shared__ float e_iou[NE];
  __shared__ float tbx[NT][4]; __shared__ int tcl[NT]; __shared__ float tat[NT];
  __shared__ int as_u[NE]; __shared__ float as_tm[NE]; __shared__ float as_iou[NE];
  __shared__ unsigned char as_f[NE];
  __shared__ unsigned mt[NT], mi[NT];
  __shared__ double red[256];

  for (int e = tid; e < NE; e += 256) {
    size_t o = (size_t)(b * NT) * KTOP + e;
    e_val[e] = top_val[o]; e_idx[e] = top_idx[o]; e_iou[e] = top_iou[o];
    as_f[e] = 0;
  }
  for (int t = tid; t < NT; t += 256) {
    const float* tg = target + (size_t)(b * NT + t) * 5;
    int tc = (int)tg[0]; tc = tc < 0 ? 0 : (tc > NC - 1 ? NC - 1 : tc);
    tcl[t] = tc;
    tbx[t][0] = tg[1]; tbx[t][1] = tg[2]; tbx[t][2] = tg[3]; tbx[t][3] = tg[4];
    tat[t] = atan_wh(tg[1], tg[2], tg[3], tg[4]);
    mt[t] = 0u; mi[t] = 0u;
  }
  __syncthreads();

  const float* pb_b = pbox + (size_t)b * NA * 4;
  const float* pc_b = pcls + (size_t)b * NA * NC;
  const float2* an2 = (const float2*)anchors;

  for (int e = tid; e < NE; e += 256) {
    float v = e_val[e];
    if (v <= 0.f) continue;
    int a = e_idx[e];
    int cnt = 0; bool first = true;
    for (int e2 = 0; e2 < NE; e2++) {
      if (e_val[e2] > 0.f && e_idx[e2] == a) {
        cnt++;
        if (e2 < e) first = false;
      }
    }
    if (!first) continue;
    int u; float tm, io;
    float bx1 = pb_b[4 * a], by1 = pb_b[4 * a + 1];
    float bx2 = pb_b[4 * a + 2], by2 = pb_b[4 * a + 3];
    float pa = atan_wh(bx1, by1, bx2, by2);
    if (cnt == 1) {
      u = e / KTOP; tm = v; io = e_iou[e];
    } else {
      // duplicate: reassign to argmax over t of clipped ciou (lowest t wins ties)
      float best = -1.f; int bu = 0;
      for (int tt = 0; tt < NT; tt++) {
        float c = ciou_pair(tbx[tt][0], tbx[tt][1], tbx[tt][2], tbx[tt][3],
                            tat[tt], bx1, by1, bx2, by2, pa);
        float cc = fminf(fmaxf(c, 0.f), 1.f);
        if (cc > best) { best = cc; bu = tt; }
      }
      u = bu; io = best;
      float2 an = an2[a];
      float gm = (tbx[u][0] < an.x && an.x < tbx[u][2] &&
                  tbx[u][1] < an.y && an.y < tbx[u][3]) ? 1.f : 0.f;
      float i2 = io * io; float i6 = i2 * i2 * i2;
      float s = pc_b[(size_t)a * NC + tcl[u]];
      float sig = 1.f / (1.f + expf(-s));
      tm = gm * i6 * sqrtf(sig);
    }
    as_f[e] = 1; as_u[e] = u; as_tm[e] = tm; as_iou[e] = io;
    atomicMax(&mt[u], __float_as_uint(tm));   // non-negative: uint order == float order
    atomicMax(&mi[u], __float_as_uint(io));
  }
  __syncthreads();

  double s1 = 0.0, s2 = 0.0, s3 = 0.0;
  for (int e = tid; e < NE; e += 256) {
    if (!as_f[e]) continue;
    int a = e_idx[e]; int u = as_u[e];
    float maxt = __uint_as_float(mt[u]);
    float maxi = __uint_as_float(mi[u]);
    float nrm = as_tm[e] / (maxt + 1e-9f) * maxi;
    s1 += (double)nrm;
    float x = pc_b[(size_t)a * NC + tcl[u]];
    s2 += (double)x * (double)nrm;
    float bx1 = pb_b[4 * a], by1 = pb_b[4 * a + 1];
    float bx2 = pb_b[4 * a + 2], by2 = pb_b[4 * a + 3];
    float c = ciou_pair(tbx[u][0], tbx[u][1], tbx[u][2], tbx[u][3], tat[u],
                        bx1, by1, bx2, by2, atan_wh(bx1, by1, bx2, by2));
    s3 += (double)((1.f - c) * nrm);
  }
  // three fixed-order tree reductions
  red[tid] = s1; __syncthreads();
  for (int off = 128; off > 0; off >>= 1) {
    if (tid < off) red[tid] += red[tid + off];
    __syncthreads();
  }
  if (tid == 0) part[b * 3 + 0] = red[0];
  __syncthreads();
  red[tid] = s2; __syncthreads();
  for (int off = 128; off > 0; off >>= 1) {
    if (tid < off) red[tid] += red[tid + off];
    __syncthreads();
  }
  if (tid == 0) part[b * 3 + 1] = red[0];
  __syncthreads();
  red[tid] = s3; __syncthreads();
  for (int off = 128; off > 0; off >>= 1) {
    if (tid < off) red[tid] += red[tid + off];
    __syncthreads();
  }
  if (tid == 0) part[b * 3 + 2] = red[0];
}

// ---- K3: softplus sum over all of predict_cls (memory-bound, 86 MB) ------
#define BCE_BLOCKS 2048
__global__ __launch_bounds__(256) void k_bce(const float* __restrict__ pcls,
                                             double* __restrict__ part) {
  const float4* p4 = (const float4*)pcls;
  const int n4 = NB * NA * NC / 4;  // 5,376,000
  double acc = 0.0;
  for (int i = blockIdx.x * 256 + threadIdx.x; i < n4; i += BCE_BLOCKS * 256) {
    float4 v = p4[i];
    acc += (double)(softplus_f(v.x) + softplus_f(v.y) +
                    softplus_f(v.z) + softplus_f(v.w));
  }
  __shared__ double red[256];
  red[threadIdx.x] = acc; __syncthreads();
  for (int off = 128; off > 0; off >>= 1) {
    if (threadIdx.x < off) red[threadIdx.x] += red[threadIdx.x + off];
    __syncthreads();
  }
  if (threadIdx.x == 0) part[blockIdx.x] = red[0];
}

// ---- K4: combine everything ----------------------------------------------
__global__ __launch_bounds__(256) void k_final(const double* __restrict__ bce_part,
                                               const double* __restrict__ k2_part,
                                               float* __restrict__ out) {
  __shared__ double red[256];
  int tid = threadIdx.x;
  double s = 0.0;
  for (int i = tid; i < BCE_BLOCKS; i += 256) s += bce_part[i];
  red[tid] = s; __syncthreads();
  for (int off = 128; off > 0; off >>= 1) {
    if (tid < off) red[tid] += red[tid + off];
    __syncthreads();
  }
  double s4 = red[0]; __syncthreads();

  red[tid] = (tid < NB) ? k2_part[3 * tid + 0] : 0.0; __syncthreads();
  for (int off = 128; off > 0; off >>= 1) {
    if (tid < off) red[tid] += red[tid + off];
    __syncthreads();
  }
  double s1 = red[0]; __syncthreads();

  red[tid] = (tid < NB) ? k2_part[3 * tid + 1] : 0.0; __syncthreads();
  for (int off = 128; off > 0; off >>= 1) {
    if (tid < off) red[tid] += red[tid + off];
    __syncthreads();
  }
  double s2 = red[0]; __syncthreads();

  red[tid] = (tid < NB) ? k2_part[3 * tid + 2] : 0.0; __syncthreads();
  for (int off = 128; off > 0; off >>= 1) {
    if (tid < off) red[tid] += red[tid + off];
    __syncthreads();
  }
  double s3 = red[0];

  if (tid == 0) {
    double cn = fmax(s1, 1.0);
    out[0] = (float)(s3 / cn);         // loss_iou
    out[1] = (float)((s4 - s2) / cn);  // loss_cls
  }
}

extern "C" void kernel_launch(void* const* d_in, const int* in_sizes, int n_in,
                              void* d_out, int out_size, void* d_ws, size_t ws_size,
                              hipStream_t stream) {
  const float* target  = (const float*)d_in[0];  // [32,64,5]
  const float* pcls    = (const float*)d_in[1];  // [32,8400,80]
  const float* pbox    = (const float*)d_in[2];  // [32,8400,4]
  const float* anchors = (const float*)d_in[3];  // [8400,2]
  float* out = (float*)d_out;

  char* ws = (char*)d_ws;
  float*  top_val = (float*)ws;                       // 20480 f = 81920 B
  int*    top_idx = (int*)(ws + 81920);               // 81920 B
  float*  top_iou = (float*)(ws + 163840);            // 81920 B
  double* k2_part = (double*)(ws + 245760);           // 32*3 doubles = 768 B
  double* k3_part = (double*)(ws + 246528);           // 2048 doubles = 16384 B
  // total ws use: 262,912 B

  k_topk<<<NB * NT, 256, 0, stream>>>(target, pcls, pbox, anchors,
                                      top_val, top_idx, top_iou);
  k_assign<<<NB, 256, 0, stream>>>(target, pcls, pbox, anchors,
                                   top_val, top_idx, top_iou, k2_part);
  k_bce<<<BCE_BLOCKS, 256, 0, stream>>>(pcls, k3_part);
  k_final<<<1, 256, 0, stream>>>(k3_part, k2_part, out);
}

// Round 3
// 225.400 us; speedup vs baseline: 1.8553x; 1.8553x over previous
//
#include <hip/hip_runtime.h>
#include <climits>
#include <cmath>

// YOLOv9 loss forward.  B=32 T=64 A=8400 C=80.
// Pipeline: k_topk (per (b,t) row top-10, grid-mask-compacted) -> k_assign
// (per batch dedup via anchor-indexed LDS tables + matched-anchor loss terms)
// -> k_bce (softplus sum over predict_cls) -> k_final (combine).
// All reductions fixed-order / order-invariant (deterministic).

#define NB 32
#define NT 64
#define NA 8400
#define NC 80
#define KTOP 10
#define CAP 4096
#define EPSF 1e-7f
#define INV_PI2 0.40528473456935108577f  // 4/pi^2

__device__ __forceinline__ float atan_wh(float x1, float y1, float x2, float y2) {
  return atanf((x2 - x1) / (y2 - y1 + EPSF));
}

__device__ __forceinline__ float ciou_pair(
    float ax1, float ay1, float ax2, float ay2, float atA,
    float bx1, float by1, float bx2, float by2, float atB)
{
  float xi1 = fmaxf(ax1, bx1), yi1 = fmaxf(ay1, by1);
  float xi2 = fminf(ax2, bx2), yi2 = fminf(ay2, by2);
  float inter = fmaxf(xi2 - xi1, 0.f) * fmaxf(yi2 - yi1, 0.f);
  float a1 = (ax2 - ax1) * (ay2 - ay1);
  float a2 = (bx2 - bx1) * (by2 - by1);
  float iou = inter / (a1 + a2 - inter + EPSF);
  float dcx = (ax2 + ax1) * 0.5f - (bx2 + bx1) * 0.5f;
  float dcy = (ay2 + ay1) * 0.5f - (by2 + by1) * 0.5f;
  float cent = dcx * dcx + dcy * dcy;
  float cw = fmaxf(ax2, bx2) - fminf(ax1, bx1);
  float ch = fmaxf(ay2, by2) - fminf(ay1, by1);
  float diag = cw * cw + ch * ch + EPSF;
  float dv = atA - atB;
  float v = INV_PI2 * dv * dv;
  float alpha = v / (v - iou + 1.f + EPSF);
  return iou - cent / diag - alpha * v;
}

__device__ __forceinline__ float softplus_f(float x) {
  return fmaxf(x, 0.f) + log1pf(expf(-fabsf(x)));
}

// ---- K1: per (b,t) row: compact grid-passing anchors, select top-10 ------
__global__ __launch_bounds__(256) void k_topk(
    const float* __restrict__ target,   // [B,T,5]
    const float* __restrict__ pcls,     // [B,A,C]
    const float* __restrict__ pbox,     // [B,A,4]
    const float* __restrict__ anchors,  // [A,2]
    float* __restrict__ top_val, int* __restrict__ top_idx,
    float* __restrict__ top_iou)
{
  int row = blockIdx.x;            // b*NT + t
  int b = row >> 6;
  const float* tg = target + (size_t)row * 5;
  float tcf = tg[0];
  float x1 = tg[1], y1 = tg[2], x2 = tg[3], y2 = tg[4];
  int tc = (int)tcf; tc = tc < 0 ? 0 : (tc > NC - 1 ? NC - 1 : tc);
  float atan_t = atan_wh(x1, y1, x2, y2);

  __shared__ int s_n;
  __shared__ float s_val[CAP];
  __shared__ int s_idx[CAP];
  __shared__ float r_val[256];
  __shared__ int r_idx[256];
  __shared__ float w_val[KTOP];
  __shared__ int w_idx[KTOP];
  if (threadIdx.x == 0) s_n = 0;
  __syncthreads();

  const float* pb_b = pbox + (size_t)b * NA * 4;
  const float* pc_b = pcls + (size_t)b * NA * NC;
  const float2* an2 = (const float2*)anchors;

  for (int a = threadIdx.x; a < NA; a += 256) {
    float2 an = an2[a];
    if (x1 < an.x && an.x < x2 && y1 < an.y && an.y < y2) {
      float bx1 = pb_b[4 * a], by1 = pb_b[4 * a + 1];
      float bx2 = pb_b[4 * a + 2], by2 = pb_b[4 * a + 3];
      float c = ciou_pair(x1, y1, x2, y2, atan_t, bx1, by1, bx2, by2,
                          atan_wh(bx1, by1, bx2, by2));
      float io = fminf(fmaxf(c, 0.f), 1.f);
      float i2 = io * io;
      float i6 = i2 * i2 * i2;
      float s = pc_b[(size_t)a * NC + tc];
      float sig = 1.f / (1.f + expf(-s));
      float tm = i6 * sqrtf(sig);
      int slot = atomicAdd(&s_n, 1);
      if (slot < CAP) { s_val[slot] = tm; s_idx[slot] = a; }
    }
  }
  __syncthreads();
  int n = s_n; if (n > CAP) n = CAP;

  // iterative top-10: (value desc, index asc) — matches lax.top_k tie-break
  for (int k = 0; k < KTOP; k++) {
    float bv = -1.f; int bi = INT_MAX;
    for (int e = threadIdx.x; e < n; e += 256) {
      float v = s_val[e]; int i = s_idx[e];
      if (v > bv || (v == bv && i < bi)) { bv = v; bi = i; }
    }
    r_val[threadIdx.x] = bv; r_idx[threadIdx.x] = bi;
    __syncthreads();
    for (int off = 128; off > 0; off >>= 1) {
      if (threadIdx.x < off) {
        float v = r_val[threadIdx.x + off]; int i = r_idx[threadIdx.x + off];
        if (v > r_val[threadIdx.x] ||
            (v == r_val[threadIdx.x] && i < r_idx[threadIdx.x])) {
          r_val[threadIdx.x] = v; r_idx[threadIdx.x] = i;
        }
      }
      __syncthreads();
    }
    if (threadIdx.x == 0) { w_val[k] = r_val[0]; w_idx[k] = r_idx[0]; }
    __syncthreads();
    int win = r_idx[0];
    if (win != INT_MAX) {
      for (int e = threadIdx.x; e < n; e += 256)
        if (s_idx[e] == win) s_val[e] = -1.f;
    }
    __syncthreads();
  }

  // write winners; recompute clipped ciou for each (10 per block, trivial)
  if (threadIdx.x < KTOP) {
    int k = threadIdx.x;
    int ai = w_idx[k]; float v = w_val[k];
    float io = 0.f;
    if (ai != INT_MAX && v > 0.f) {
      float bx1 = pb_b[4 * ai], by1 = pb_b[4 * ai + 1];
      float bx2 = pb_b[4 * ai + 2], by2 = pb_b[4 * ai + 3];
      float c = ciou_pair(x1, y1, x2, y2, atan_t, bx1, by1, bx2, by2,
                          atan_wh(bx1, by1, bx2, by2));
      io = fminf(fmaxf(c, 0.f), 1.f);
    } else { ai = -1; v = 0.f; }
    size_t o = (size_t)row * KTOP + k;
    top_val[o] = v; top_idx[o] = ai; top_iou[o] = io;
  }
}

// ---- K2: per-batch dedup (anchor-indexed LDS tables) + loss terms --------
__global__ __launch_bounds__(256) void k_assign(
    const float* __restrict__ target, const float* __restrict__ pcls,
    const float* __restrict__ pbox, const float* __restrict__ anchors,
    const float* __restrict__ top_val, const int* __restrict__ top_idx,
    const float* __restrict__ top_iou,
    double* __restrict__ part /* [NB][3] */)
{
  int b = blockIdx.x;
  int tid = threadIdx.x;
  const int NE = NT * KTOP;  // 640 candidate entries

  __shared__ float e_val[NE]; __shared__ int e_idx[NE]; __shared__ float e_iou[NE];
  __shared__ float tbx[NT][4]; __shared__ int tcl[NT]; __shared__ float tat[NT];
  __shared__ int as_u[NE]; __shared__ float as_tm[NE];
  __shared__ unsigned char as_f[NE];
  __shared__ unsigned mt[NT], mi[NT];
  __shared__ double red[256];
  __shared__ int cnt[NA];    // per-anchor occurrence count  (33.6 KB)
  __shared__ int first[NA];  // per-anchor min entry index   (33.6 KB)

  for (int a = tid; a < NA; a += 256) { cnt[a] = 0; first[a] = INT_MAX; }
  for (int e = tid; e < NE; e += 256) {
    size_t o = (size_t)(b * NT) * KTOP + e;
    e_val[e] = top_val[o]; e_idx[e] = top_idx[o]; e_iou[e] = top_iou[o];
    as_f[e] = 0;
  }
  for (int t = tid; t < NT; t += 256) {
    const float* tg = target + (size_t)(b * NT + t) * 5;
    int tc = (int)tg[0]; tc = tc < 0 ? 0 : (tc > NC - 1 ? NC - 1 : tc);
    tcl[t] = tc;
    tbx[t][0] = tg[1]; tbx[t][1] = tg[2]; tbx[t][2] = tg[3]; tbx[t][3] = tg[4];
    tat[t] = atan_wh(tg[1], tg[2], tg[3], tg[4]);
    mt[t] = 0u; mi[t] = 0u;
  }
  __syncthreads();

  // phase 1: per-anchor count + first occurrence (order-invariant atomics)
  for (int e = tid; e < NE; e += 256) {
    if (e_val[e] > 0.f) {
      int a = e_idx[e];
      atomicAdd(&cnt[a], 1);
      atomicMin(&first[a], e);
    }
  }
  __syncthreads();

  const float* pb_b = pbox + (size_t)b * NA * 4;
  const float* pc_b = pcls + (size_t)b * NA * NC;
  const float2* an2 = (const float2*)anchors;

  // phase 2: representatives resolve their anchor's assignment
  for (int e = tid; e < NE; e += 256) {
    float v = e_val[e];
    if (v <= 0.f) continue;
    int a = e_idx[e];
    if (first[a] != e) continue;   // not the representative entry
    int u; float tm, io;
    if (cnt[a] == 1) {
      u = e / KTOP; tm = v; io = e_iou[e];
    } else {
      // duplicate: reassign to argmax over t of clipped ciou (first t wins ties)
      float bx1 = pb_b[4 * a], by1 = pb_b[4 * a + 1];
      float bx2 = pb_b[4 * a + 2], by2 = pb_b[4 * a + 3];
      float pa = atan_wh(bx1, by1, bx2, by2);
      float best = -1.f; int bu = 0;
      for (int tt = 0; tt < NT; tt++) {
        float c = ciou_pair(tbx[tt][0], tbx[tt][1], tbx[tt][2], tbx[tt][3],
                            tat[tt], bx1, by1, bx2, by2, pa);
        float cc = fminf(fmaxf(c, 0.f), 1.f);
        if (cc > best) { best = cc; bu = tt; }
      }
      u = bu; io = best;
      float2 an = an2[a];
      float gm = (tbx[u][0] < an.x && an.x < tbx[u][2] &&
                  tbx[u][1] < an.y && an.y < tbx[u][3]) ? 1.f : 0.f;
      float i2 = io * io; float i6 = i2 * i2 * i2;
      float s = pc_b[(size_t)a * NC + tcl[u]];
      float sig = 1.f / (1.f + expf(-s));
      tm = gm * i6 * sqrtf(sig);
    }
    as_f[e] = 1; as_u[e] = u; as_tm[e] = tm;
    atomicMax(&mt[u], __float_as_uint(tm));   // non-negative: uint order == float order
    atomicMax(&mi[u], __float_as_uint(io));
  }
  __syncthreads();

  double s1 = 0.0, s2 = 0.0, s3 = 0.0;
  for (int e = tid; e < NE; e += 256) {
    if (!as_f[e]) continue;
    int a = e_idx[e]; int u = as_u[e];
    float maxt = __uint_as_float(mt[u]);
    float maxi = __uint_as_float(mi[u]);
    float nrm = as_tm[e] / (maxt + 1e-9f) * maxi;
    s1 += (double)nrm;
    float x = pc_b[(size_t)a * NC + tcl[u]];
    s2 += (double)x * (double)nrm;
    float bx1 = pb_b[4 * a], by1 = pb_b[4 * a + 1];
    float bx2 = pb_b[4 * a + 2], by2 = pb_b[4 * a + 3];
    float c = ciou_pair(tbx[u][0], tbx[u][1], tbx[u][2], tbx[u][3], tat[u],
                        bx1, by1, bx2, by2, atan_wh(bx1, by1, bx2, by2));
    s3 += (double)((1.f - c) * nrm);
  }
  // three fixed-order tree reductions
  red[tid] = s1; __syncthreads();
  for (int off = 128; off > 0; off >>= 1) {
    if (tid < off) red[tid] += red[tid + off];
    __syncthreads();
  }
  if (tid == 0) part[b * 3 + 0] = red[0];
  __syncthreads();
  red[tid] = s2; __syncthreads();
  for (int off = 128; off > 0; off >>= 1) {
    if (tid < off) red[tid] += red[tid + off];
    __syncthreads();
  }
  if (tid == 0) part[b * 3 + 1] = red[0];
  __syncthreads();
  red[tid] = s3; __syncthreads();
  for (int off = 128; off > 0; off >>= 1) {
    if (tid < off) red[tid] += red[tid + off];
    __syncthreads();
  }
  if (tid == 0) part[b * 3 + 2] = red[0];
}

// ---- K3: softplus sum over all of predict_cls (memory-bound, 86 MB) ------
#define BCE_BLOCKS 2048
__global__ __launch_bounds__(256) void k_bce(const float* __restrict__ pcls,
                                             double* __restrict__ part) {
  const float4* p4 = (const float4*)pcls;
  const int n4 = NB * NA * NC / 4;  // 5,376,000
  double acc = 0.0;
  for (int i = blockIdx.x * 256 + threadIdx.x; i < n4; i += BCE_BLOCKS * 256) {
    float4 v = p4[i];
    acc += (double)(softplus_f(v.x) + softplus_f(v.y) +
                    softplus_f(v.z) + softplus_f(v.w));
  }
  __shared__ double red[256];
  red[threadIdx.x] = acc; __syncthreads();
  for (int off = 128; off > 0; off >>= 1) {
    if (threadIdx.x < off) red[threadIdx.x] += red[threadIdx.x + off];
    __syncthreads();
  }
  if (threadIdx.x == 0) part[blockIdx.x] = red[0];
}

// ---- K4: combine everything ----------------------------------------------
__global__ __launch_bounds__(256) void k_final(const double* __restrict__ bce_part,
                                               const double* __restrict__ k2_part,
                                               float* __restrict__ out) {
  __shared__ double red[256];
  int tid = threadIdx.x;
  double s = 0.0;
  for (int i = tid; i < BCE_BLOCKS; i += 256) s += bce_part[i];
  red[tid] = s; __syncthreads();
  for (int off = 128; off > 0; off >>= 1) {
    if (tid < off) red[tid] += red[tid + off];
    __syncthreads();
  }
  double s4 = red[0]; __syncthreads();

  red[tid] = (tid < NB) ? k2_part[3 * tid + 0] : 0.0; __syncthreads();
  for (int off = 128; off > 0; off >>= 1) {
    if (tid < off) red[tid] += red[tid + off];
    __syncthreads();
  }
  double s1 = red[0]; __syncthreads();

  red[tid] = (tid < NB) ? k2_part[3 * tid + 1] : 0.0; __syncthreads();
  for (int off = 128; off > 0; off >>= 1) {
    if (tid < off) red[tid] += red[tid + off];
    __syncthreads();
  }
  double s2 = red[0]; __syncthreads();

  red[tid] = (tid < NB) ? k2_part[3 * tid + 2] : 0.0; __syncthreads();
  for (int off = 128; off > 0; off >>= 1) {
    if (tid < off) red[tid] += red[tid + off];
    __syncthreads();
  }
  double s3 = red[0];

  if (tid == 0) {
    double cn = fmax(s1, 1.0);
    out[0] = (float)(s3 / cn);         // loss_iou
    out[1] = (float)((s4 - s2) / cn);  // loss_cls
  }
}

extern "C" void kernel_launch(void* const* d_in, const int* in_sizes, int n_in,
                              void* d_out, int out_size, void* d_ws, size_t ws_size,
                              hipStream_t stream) {
  const float* target  = (const float*)d_in[0];  // [32,64,5]
  const float* pcls    = (const float*)d_in[1];  // [32,8400,80]
  const float* pbox    = (const float*)d_in[2];  // [32,8400,4]
  const float* anchors = (const float*)d_in[3];  // [8400,2]
  float* out = (float*)d_out;

  char* ws = (char*)d_ws;
  float*  top_val = (float*)ws;                       // 20480 f = 81920 B
  int*    top_idx = (int*)(ws + 81920);               // 81920 B
  float*  top_iou = (float*)(ws + 163840);            // 81920 B
  double* k2_part = (double*)(ws + 245760);           // 32*3 doubles = 768 B
  double* k3_part = (double*)(ws + 246528);           // 2048 doubles = 16384 B
  // total ws use: 262,912 B

  k_topk<<<NB * NT, 256, 0, stream>>>(target, pcls, pbox, anchors,
                                      top_val, top_idx, top_iou);
  k_assign<<<NB, 256, 0, stream>>>(target, pcls, pbox, anchors,
                                   top_val, top_idx, top_iou, k2_part);
  k_bce<<<BCE_BLOCKS, 256, 0, stream>>>(pcls, k3_part);
  k_final<<<1, 256, 0, stream>>>(k3_part, k2_part, out);
}

// Round 4
// 164.831 us; speedup vs baseline: 2.5371x; 1.3675x over previous
//
#include <hip/hip_runtime.h>
#include <climits>
#include <cmath>

// YOLOv9 loss forward.  B=32 T=64 A=8400 C=80.
// Pipeline: k_topk (per (b,t) row top-10 + zero mt/mi tables) ->
// k_resolve (one WAVE per candidate entry: dedup via wave-scan, duplicate
// argmax via one-target-per-lane, precompute per-entry loss terms) ->
// k_sums (per-batch fixed-order reduction of precomputed terms) ->
// k_bce (softplus sum over predict_cls) -> k_final (combine).
// All cross-thread combines are order-invariant atomics (max/add-int) or
// fixed-order trees -> deterministic across graph replays.

#define NB 32
#define NT 64
#define NA 8400
#define NC 80
#define KTOP 10
#define NE (NT * KTOP)   // 640 entries per batch
#define CAP 4096
#define EPSF 1e-7f
#define INV_PI2 0.40528473456935108577f  // 4/pi^2

__device__ __forceinline__ float atan_wh(float x1, float y1, float x2, float y2) {
  return atanf((x2 - x1) / (y2 - y1 + EPSF));
}

__device__ __forceinline__ float ciou_pair(
    float ax1, float ay1, float ax2, float ay2, float atA,
    float bx1, float by1, float bx2, float by2, float atB)
{
  float xi1 = fmaxf(ax1, bx1), yi1 = fmaxf(ay1, by1);
  float xi2 = fminf(ax2, bx2), yi2 = fminf(ay2, by2);
  float inter = fmaxf(xi2 - xi1, 0.f) * fmaxf(yi2 - yi1, 0.f);
  float a1 = (ax2 - ax1) * (ay2 - ay1);
  float a2 = (bx2 - bx1) * (by2 - by1);
  float iou = inter / (a1 + a2 - inter + EPSF);
  float dcx = (ax2 + ax1) * 0.5f - (bx2 + bx1) * 0.5f;
  float dcy = (ay2 + ay1) * 0.5f - (by2 + by1) * 0.5f;
  float cent = dcx * dcx + dcy * dcy;
  float cw = fmaxf(ax2, bx2) - fminf(ax1, bx1);
  float ch = fmaxf(ay2, by2) - fminf(ay1, by1);
  float diag = cw * cw + ch * ch + EPSF;
  float dv = atA - atB;
  float v = INV_PI2 * dv * dv;
  float alpha = v / (v - iou + 1.f + EPSF);
  return iou - cent / diag - alpha * v;
}

__device__ __forceinline__ float softplus_f(float x) {
  return fmaxf(x, 0.f) + log1pf(expf(-fabsf(x)));
}

// ---- K1: per (b,t) row: compact grid-passing anchors, select top-10 ------
__global__ __launch_bounds__(256) void k_topk(
    const float* __restrict__ target,   // [B,T,5]
    const float* __restrict__ pcls,     // [B,A,C]
    const float* __restrict__ pbox,     // [B,A,4]
    const float* __restrict__ anchors,  // [A,2]
    float* __restrict__ top_val, int* __restrict__ top_idx,
    float* __restrict__ top_iou,
    unsigned* __restrict__ mtg, unsigned* __restrict__ mig)
{
  int row = blockIdx.x;            // b*NT + t   (grid is exactly NB*NT)
  if (threadIdx.x == 0) { mtg[row] = 0u; mig[row] = 0u; }  // zero max tables
  int b = row >> 6;
  const float* tg = target + (size_t)row * 5;
  float tcf = tg[0];
  float x1 = tg[1], y1 = tg[2], x2 = tg[3], y2 = tg[4];
  int tc = (int)tcf; tc = tc < 0 ? 0 : (tc > NC - 1 ? NC - 1 : tc);
  float atan_t = atan_wh(x1, y1, x2, y2);

  __shared__ int s_n;
  __shared__ float s_val[CAP];
  __shared__ int s_idx[CAP];
  __shared__ float r_val[256];
  __shared__ int r_idx[256];
  __shared__ float w_val[KTOP];
  __shared__ int w_idx[KTOP];
  if (threadIdx.x == 0) s_n = 0;
  __syncthreads();

  const float* pb_b = pbox + (size_t)b * NA * 4;
  const float* pc_b = pcls + (size_t)b * NA * NC;
  const float2* an2 = (const float2*)anchors;

  for (int a = threadIdx.x; a < NA; a += 256) {
    float2 an = an2[a];
    if (x1 < an.x && an.x < x2 && y1 < an.y && an.y < y2) {
      float bx1 = pb_b[4 * a], by1 = pb_b[4 * a + 1];
      float bx2 = pb_b[4 * a + 2], by2 = pb_b[4 * a + 3];
      float c = ciou_pair(x1, y1, x2, y2, atan_t, bx1, by1, bx2, by2,
                          atan_wh(bx1, by1, bx2, by2));
      float io = fminf(fmaxf(c, 0.f), 1.f);
      float i2 = io * io;
      float i6 = i2 * i2 * i2;
      float s = pc_b[(size_t)a * NC + tc];
      float sig = 1.f / (1.f + expf(-s));
      float tm = i6 * sqrtf(sig);
      int slot = atomicAdd(&s_n, 1);
      if (slot < CAP) { s_val[slot] = tm; s_idx[slot] = a; }
    }
  }
  __syncthreads();
  int n = s_n; if (n > CAP) n = CAP;

  // iterative top-10: (value desc, index asc) — matches lax.top_k tie-break
  for (int k = 0; k < KTOP; k++) {
    float bv = -1.f; int bi = INT_MAX;
    for (int e = threadIdx.x; e < n; e += 256) {
      float v = s_val[e]; int i = s_idx[e];
      if (v > bv || (v == bv && i < bi)) { bv = v; bi = i; }
    }
    r_val[threadIdx.x] = bv; r_idx[threadIdx.x] = bi;
    __syncthreads();
    for (int off = 128; off > 0; off >>= 1) {
      if (threadIdx.x < off) {
        float v = r_val[threadIdx.x + off]; int i = r_idx[threadIdx.x + off];
        if (v > r_val[threadIdx.x] ||
            (v == r_val[threadIdx.x] && i < r_idx[threadIdx.x])) {
          r_val[threadIdx.x] = v; r_idx[threadIdx.x] = i;
        }
      }
      __syncthreads();
    }
    if (threadIdx.x == 0) { w_val[k] = r_val[0]; w_idx[k] = r_idx[0]; }
    __syncthreads();
    int win = r_idx[0];
    if (win != INT_MAX) {
      for (int e = threadIdx.x; e < n; e += 256)
        if (s_idx[e] == win) s_val[e] = -1.f;
    }
    __syncthreads();
  }

  // write winners; recompute clipped ciou for each (10 per block, trivial)
  if (threadIdx.x < KTOP) {
    int k = threadIdx.x;
    int ai = w_idx[k]; float v = w_val[k];
    float io = 0.f;
    if (ai != INT_MAX && v > 0.f) {
      float bx1 = pb_b[4 * ai], by1 = pb_b[4 * ai + 1];
      float bx2 = pb_b[4 * ai + 2], by2 = pb_b[4 * ai + 3];
      float c = ciou_pair(x1, y1, x2, y2, atan_t, bx1, by1, bx2, by2,
                          atan_wh(bx1, by1, bx2, by2));
      io = fminf(fmaxf(c, 0.f), 1.f);
    } else { ai = -1; v = 0.f; }
    size_t o = (size_t)row * KTOP + k;
    top_val[o] = v; top_idx[o] = ai; top_iou[o] = io;
  }
}

// ---- K2: one wave per entry: dedup + resolve + per-entry loss terms ------
__global__ __launch_bounds__(256) void k_resolve(
    const float* __restrict__ target, const float* __restrict__ pcls,
    const float* __restrict__ pbox, const float* __restrict__ anchors,
    const float* __restrict__ top_val, const int* __restrict__ top_idx,
    const float* __restrict__ top_iou,
    float* __restrict__ as_tm, float* __restrict__ as_x,
    float* __restrict__ as_cio, int* __restrict__ as_u,
    unsigned* __restrict__ mtg, unsigned* __restrict__ mig)
{
  int gid = blockIdx.x * 256 + threadIdx.x;
  int entry = gid >> 6;            // one 64-lane wave per entry
  int lane = threadIdx.x & 63;
  int b = entry / NE;
  int el = entry - b * NE;

  const float* bv = top_val + (size_t)b * NE;
  const int* bix = top_idx + (size_t)b * NE;
  float v = bv[el];
  int a = bix[el];

  bool dead = (v <= 0.f);
  int cnt = 0, first = NE;
  if (!dead) {
    // wave-parallel scan of this batch's 640 entries (L2-hot, coalesced)
    for (int s = lane; s < NE; s += 64) {
      float v2 = bv[s]; int a2 = bix[s];
      if (v2 > 0.f && a2 == a) { cnt++; if (s < first) first = s; }
    }
    for (int off = 32; off > 0; off >>= 1) {
      cnt += __shfl_xor(cnt, off);
      int of = __shfl_xor(first, off);
      first = of < first ? of : first;
    }
    if (first != el) dead = true;   // not the representative entry
  }
  if (dead) {
    if (lane == 0) { as_tm[entry] = 0.f; as_x[entry] = 0.f;
                     as_cio[entry] = 0.f; as_u[entry] = 0; }
    return;
  }

  const float* pb = pbox + ((size_t)b * NA + a) * 4;
  int u; float tm = -1.f, io;
  if (cnt == 1) {
    u = el / KTOP; tm = v; io = top_iou[entry];
  } else {
    // duplicate: argmax over the 64 targets of clipped ciou, one per lane
    const float* tg = target + (size_t)(b * NT + lane) * 5;
    float tx1 = tg[1], ty1 = tg[2], tx2 = tg[3], ty2 = tg[4];
    float ta = atan_wh(tx1, ty1, tx2, ty2);
    float bx1 = pb[0], by1 = pb[1], bx2 = pb[2], by2 = pb[3];
    float pa = atan_wh(bx1, by1, bx2, by2);
    float c = ciou_pair(tx1, ty1, tx2, ty2, ta, bx1, by1, bx2, by2, pa);
    float cc = fminf(fmaxf(c, 0.f), 1.f);
    float best = cc; int bu = lane;
    for (int off = 32; off > 0; off >>= 1) {
      float ob = __shfl_xor(best, off);
      int ou = __shfl_xor(bu, off);
      if (ob > best || (ob == best && ou < bu)) { best = ob; bu = ou; }
    }
    u = bu; io = best;               // lowest-t tie-break == jnp.argmax
  }

  if (lane == 0) {
    const float* tgu = target + (size_t)(b * NT + u) * 5;
    float ux1 = tgu[1], uy1 = tgu[2], ux2 = tgu[3], uy2 = tgu[4];
    int cu = (int)tgu[0]; cu = cu < 0 ? 0 : (cu > NC - 1 ? NC - 1 : cu);
    float x = pcls[((size_t)b * NA + a) * NC + cu];
    if (cnt != 1) {
      float2 an = ((const float2*)anchors)[a];
      float gm = (ux1 < an.x && an.x < ux2 && uy1 < an.y && an.y < uy2) ? 1.f : 0.f;
      float i2 = io * io; float i6 = i2 * i2 * i2;
      float sig = 1.f / (1.f + expf(-x));
      tm = gm * i6 * sqrtf(sig);
    }
    float bx1 = pb[0], by1 = pb[1], bx2 = pb[2], by2 = pb[3];
    float c = ciou_pair(ux1, uy1, ux2, uy2, atan_wh(ux1, uy1, ux2, uy2),
                        bx1, by1, bx2, by2, atan_wh(bx1, by1, bx2, by2));
    as_tm[entry] = tm; as_x[entry] = x; as_cio[entry] = 1.f - c; as_u[entry] = u;
    atomicMax(&mtg[b * NT + u], __float_as_uint(tm));  // non-neg: uint order == float order
    atomicMax(&mig[b * NT + u], __float_as_uint(io));
  }
}

// ---- K3: per-batch fixed-order reduction of precomputed terms ------------
__global__ __launch_bounds__(256) void k_sums(
    const float* __restrict__ as_tm, const float* __restrict__ as_x,
    const float* __restrict__ as_cio, const int* __restrict__ as_u,
    const unsigned* __restrict__ mtg, const unsigned* __restrict__ mig,
    double* __restrict__ part /* [NB][3] */)
{
  int b = blockIdx.x;
  int tid = threadIdx.x;
  __shared__ double red[256];

  double s1 = 0.0, s2 = 0.0, s3 = 0.0;
  for (int e = tid; e < NE; e += 256) {
    size_t o = (size_t)b * NE + e;
    float tm = as_tm[o];
    int u = as_u[o];
    float maxt = __uint_as_float(mtg[b * NT + u]);
    float maxi = __uint_as_float(mig[b * NT + u]);
    float nrm = tm / (maxt + 1e-9f) * maxi;   // exact 0 for dead entries
    s1 += (double)nrm;
    s2 += (double)as_x[o] * (double)nrm;
    s3 += (double)(as_cio[o] * nrm);
  }
  red[tid] = s1; __syncthreads();
  for (int off = 128; off > 0; off >>= 1) {
    if (tid < off) red[tid] += red[tid + off];
    __syncthreads();
  }
  if (tid == 0) part[b * 3 + 0] = red[0];
  __syncthreads();
  red[tid] = s2; __syncthreads();
  for (int off = 128; off > 0; off >>= 1) {
    if (tid < off) red[tid] += red[tid + off];
    __syncthreads();
  }
  if (tid == 0) part[b * 3 + 1] = red[0];
  __syncthreads();
  red[tid] = s3; __syncthreads();
  for (int off = 128; off > 0; off >>= 1) {
    if (tid < off) red[tid] += red[tid + off];
    __syncthreads();
  }
  if (tid == 0) part[b * 3 + 2] = red[0];
}

// ---- K4: softplus sum over all of predict_cls (memory-bound, 86 MB) ------
#define BCE_BLOCKS 2048
__global__ __launch_bounds__(256) void k_bce(const float* __restrict__ pcls,
                                             double* __restrict__ part) {
  const float4* p4 = (const float4*)pcls;
  const int n4 = NB * NA * NC / 4;  // 5,376,000
  double acc = 0.0;
  for (int i = blockIdx.x * 256 + threadIdx.x; i < n4; i += BCE_BLOCKS * 256) {
    float4 v = p4[i];
    acc += (double)(softplus_f(v.x) + softplus_f(v.y) +
                    softplus_f(v.z) + softplus_f(v.w));
  }
  __shared__ double red[256];
  red[threadIdx.x] = acc; __syncthreads();
  for (int off = 128; off > 0; off >>= 1) {
    if (threadIdx.x < off) red[threadIdx.x] += red[threadIdx.x + off];
    __syncthreads();
  }
  if (threadIdx.x == 0) part[blockIdx.x] = red[0];
}

// ---- K5: combine everything ----------------------------------------------
__global__ __launch_bounds__(256) void k_final(const double* __restrict__ bce_part,
                                               const double* __restrict__ k2_part,
                                               float* __restrict__ out) {
  __shared__ double red[256];
  int tid = threadIdx.x;
  double s = 0.0;
  for (int i = tid; i < BCE_BLOCKS; i += 256) s += bce_part[i];
  red[tid] = s; __syncthreads();
  for (int off = 128; off > 0; off >>= 1) {
    if (tid < off) red[tid] += red[tid + off];
    __syncthreads();
  }
  double s4 = red[0]; __syncthreads();

  red[tid] = (tid < NB) ? k2_part[3 * tid + 0] : 0.0; __syncthreads();
  for (int off = 128; off > 0; off >>= 1) {
    if (tid < off) red[tid] += red[tid + off];
    __syncthreads();
  }
  double s1 = red[0]; __syncthreads();

  red[tid] = (tid < NB) ? k2_part[3 * tid + 1] : 0.0; __syncthreads();
  for (int off = 128; off > 0; off >>= 1) {
    if (tid < off) red[tid] += red[tid + off];
    __syncthreads();
  }
  double s2 = red[0]; __syncthreads();

  red[tid] = (tid < NB) ? k2_part[3 * tid + 2] : 0.0; __syncthreads();
  for (int off = 128; off > 0; off >>= 1) {
    if (tid < off) red[tid] += red[tid + off];
    __syncthreads();
  }
  double s3 = red[0];

  if (tid == 0) {
    double cn = fmax(s1, 1.0);
    out[0] = (float)(s3 / cn);         // loss_iou
    out[1] = (float)((s4 - s2) / cn);  // loss_cls
  }
}

extern "C" void kernel_launch(void* const* d_in, const int* in_sizes, int n_in,
                              void* d_out, int out_size, void* d_ws, size_t ws_size,
                              hipStream_t stream) {
  const float* target  = (const float*)d_in[0];  // [32,64,5]
  const float* pcls    = (const float*)d_in[1];  // [32,8400,80]
  const float* pbox    = (const float*)d_in[2];  // [32,8400,4]
  const float* anchors = (const float*)d_in[3];  // [8400,2]
  float* out = (float*)d_out;

  char* ws = (char*)d_ws;
  float*    top_val = (float*)ws;                    // 20480 f  =  81,920 B
  int*      top_idx = (int*)(ws + 81920);            //             81,920 B
  float*    top_iou = (float*)(ws + 163840);         //             81,920 B
  float*    as_tm   = (float*)(ws + 245760);         //             81,920 B
  float*    as_x    = (float*)(ws + 327680);         //             81,920 B
  float*    as_cio  = (float*)(ws + 409600);         //             81,920 B
  int*      as_u    = (int*)(ws + 491520);           //             81,920 B
  unsigned* mtg     = (unsigned*)(ws + 573440);      // 2048 u   =   8,192 B
  unsigned* mig     = (unsigned*)(ws + 581632);      //              8,192 B
  double*   k2_part = (double*)(ws + 589824);        // 96 d     =     768 B
  double*   k3_part = (double*)(ws + 590592);        // 2048 d   =  16,384 B
  // total ws use: 606,976 B

  k_topk<<<NB * NT, 256, 0, stream>>>(target, pcls, pbox, anchors,
                                      top_val, top_idx, top_iou, mtg, mig);
  k_resolve<<<(NB * NE * 64) / 256, 256, 0, stream>>>(
      target, pcls, pbox, anchors, top_val, top_idx, top_iou,
      as_tm, as_x, as_cio, as_u, mtg, mig);
  k_sums<<<NB, 256, 0, stream>>>(as_tm, as_x, as_cio, as_u, mtg, mig, k2_part);
  k_bce<<<BCE_BLOCKS, 256, 0, stream>>>(pcls, k3_part);
  k_final<<<1, 256, 0, stream>>>(k3_part, k2_part, out);
}

// Round 6
// 141.951 us; speedup vs baseline: 2.9460x; 1.1612x over previous
//
#include <hip/hip_runtime.h>
#include <climits>
#include <cmath>

// YOLOv9 loss forward.  B=32 T=64 A=8400 C=80.
// Pipeline: k_topk (per (b,t) row top-10 via register/wave selection) ->
// k_resolve (one wave per candidate entry) -> k_sums -> k_bce -> k_final.
// All cross-thread combines are order-invariant atomics or fixed-order
// trees -> deterministic across graph replays.

#define NB 32
#define NT 64
#define NA 8400
#define NC 80
#define KTOP 10
#define NE (NT * KTOP)   // 640 entries per batch
#define CAP 1024         // max compacted candidates (worst case ~650)
#define EPSF 1e-7f
#define INV_PI2 0.40528473456935108577f  // 4/pi^2

__device__ __forceinline__ float atan_wh(float x1, float y1, float x2, float y2) {
  return atanf((x2 - x1) / (y2 - y1 + EPSF));
}

__device__ __forceinline__ float ciou_pair(
    float ax1, float ay1, float ax2, float ay2, float atA,
    float bx1, float by1, float bx2, float by2, float atB)
{
  float xi1 = fmaxf(ax1, bx1), yi1 = fmaxf(ay1, by1);
  float xi2 = fminf(ax2, bx2), yi2 = fminf(ay2, by2);
  float inter = fmaxf(xi2 - xi1, 0.f) * fmaxf(yi2 - yi1, 0.f);
  float a1 = (ax2 - ax1) * (ay2 - ay1);
  float a2 = (bx2 - bx1) * (by2 - by1);
  float iou = inter / (a1 + a2 - inter + EPSF);
  float dcx = (ax2 + ax1) * 0.5f - (bx2 + bx1) * 0.5f;
  float dcy = (ay2 + ay1) * 0.5f - (by2 + by1) * 0.5f;
  float cent = dcx * dcx + dcy * dcy;
  float cw = fmaxf(ax2, bx2) - fminf(ax1, bx1);
  float ch = fmaxf(ay2, by2) - fminf(ay1, by1);
  float diag = cw * cw + ch * ch + EPSF;
  float dv = atA - atB;
  float v = INV_PI2 * dv * dv;
  float alpha = v / (v - iou + 1.f + EPSF);
  return iou - cent / diag - alpha * v;
}

__device__ __forceinline__ float softplus_f(float x) {
  return fmaxf(x, 0.f) + log1pf(expf(-fabsf(x)));
}

// ---- K1: per (b,t) row: compact grid-passing anchors, top-10 in regs -----
__global__ __launch_bounds__(256) void k_topk(
    const float* __restrict__ target,   // [B,T,5]
    const float* __restrict__ pcls,     // [B,A,C]
    const float* __restrict__ pbox,     // [B,A,4]
    const float* __restrict__ anchors,  // [A,2]
    float* __restrict__ top_val, int* __restrict__ top_idx,
    float* __restrict__ top_iou,
    unsigned* __restrict__ mtg, unsigned* __restrict__ mig)
{
  int row = blockIdx.x;            // b*NT + t   (grid is exactly NB*NT)
  int tid = threadIdx.x;
  if (tid == 0) { mtg[row] = 0u; mig[row] = 0u; }  // zero max tables
  int b = row >> 6;
  const float* tg = target + (size_t)row * 5;
  float tcf = tg[0];
  float x1 = tg[1], y1 = tg[2], x2 = tg[3], y2 = tg[4];
  int tc = (int)tcf; tc = tc < 0 ? 0 : (tc > NC - 1 ? NC - 1 : tc);
  float atan_t = atan_wh(x1, y1, x2, y2);

  __shared__ int s_n;
  __shared__ float s_val[CAP];
  __shared__ int s_idx[CAP];
  __shared__ float xw_v[4];  __shared__ int xw_a[4];
  __shared__ float w_val[KTOP]; __shared__ int w_idx[KTOP];
  if (tid == 0) s_n = 0;
  __syncthreads();

  const float* pb_b = pbox + (size_t)b * NA * 4;
  const float* pc_b = pcls + (size_t)b * NA * NC;
  const float4* an4 = (const float4*)anchors;   // 2 anchors per float4

  for (int p = tid; p < NA / 2; p += 256) {
    float4 aa = an4[p];
#pragma unroll
    for (int h = 0; h < 2; h++) {
      int a = 2 * p + h;
      float anx = h ? aa.z : aa.x;
      float any_ = h ? aa.w : aa.y;
      if (x1 < anx && anx < x2 && y1 < any_ && any_ < y2) {
        float4 bb = ((const float4*)pb_b)[a];
        float c = ciou_pair(x1, y1, x2, y2, atan_t, bb.x, bb.y, bb.z, bb.w,
                            atan_wh(bb.x, bb.y, bb.z, bb.w));
        float io = fminf(fmaxf(c, 0.f), 1.f);
        float i2 = io * io;
        float i6 = i2 * i2 * i2;
        float s = pc_b[(size_t)a * NC + tc];
        float sig = 1.f / (1.f + expf(-s));
        float tm = i6 * sqrtf(sig);
        int slot = atomicAdd(&s_n, 1);
        if (slot < CAP) { s_val[slot] = tm; s_idx[slot] = a; }
      }
    }
  }
  __syncthreads();
  int n = s_n; if (n > CAP) n = CAP;

  // load candidates into 4 static register slots per thread
  float v0 = -1.f, v1 = -1.f, v2 = -1.f, v3 = -1.f;
  int a0 = INT_MAX, a1 = INT_MAX, a2 = INT_MAX, a3 = INT_MAX;
  if (tid < n)       { v0 = s_val[tid];       a0 = s_idx[tid]; }
  if (tid + 256 < n) { v1 = s_val[tid + 256]; a1 = s_idx[tid + 256]; }
  if (tid + 512 < n) { v2 = s_val[tid + 512]; a2 = s_idx[tid + 512]; }
  if (tid + 768 < n) { v3 = s_val[tid + 768]; a3 = s_idx[tid + 768]; }

  // 10 rounds: local 4-max -> wave butterfly -> 4-wave LDS merge -> kill.
  // Tie-break everywhere: (value desc, anchor index asc) == lax.top_k.
  for (int k = 0; k < KTOP; k++) {
    float bv = v0; int ba = a0;
    if (v1 > bv || (v1 == bv && a1 < ba)) { bv = v1; ba = a1; }
    if (v2 > bv || (v2 == bv && a2 < ba)) { bv = v2; ba = a2; }
    if (v3 > bv || (v3 == bv && a3 < ba)) { bv = v3; ba = a3; }
#pragma unroll
    for (int off = 32; off > 0; off >>= 1) {
      float ov = __shfl_xor(bv, off); int oa = __shfl_xor(ba, off);
      if (ov > bv || (ov == bv && oa < ba)) { bv = ov; ba = oa; }
    }
    if ((tid & 63) == 0) { xw_v[tid >> 6] = bv; xw_a[tid >> 6] = ba; }
    __syncthreads();
    float fv = xw_v[0]; int fa = xw_a[0];
    { float ov = xw_v[1]; int oa = xw_a[1];
      if (ov > fv || (ov == fv && oa < fa)) { fv = ov; fa = oa; } }
    { float ov = xw_v[2]; int oa = xw_a[2];
      if (ov > fv || (ov == fv && oa < fa)) { fv = ov; fa = oa; } }
    { float ov = xw_v[3]; int oa = xw_a[3];
      if (ov > fv || (ov == fv && oa < fa)) { fv = ov; fa = oa; } }
    if (tid == 0) { w_val[k] = fv; w_idx[k] = fa; }
    // kill winner (anchor indices unique; sentinel-kill is a no-op)
    if (a0 == fa) { v0 = -1.f; a0 = INT_MAX; }
    if (a1 == fa) { v1 = -1.f; a1 = INT_MAX; }
    if (a2 == fa) { v2 = -1.f; a2 = INT_MAX; }
    if (a3 == fa) { v3 = -1.f; a3 = INT_MAX; }
    __syncthreads();
  }

  // write winners; recompute clipped ciou for each (10 per block, trivial)
  if (tid < KTOP) {
    int k = tid;
    int ai = w_idx[k]; float v = w_val[k];
    float io = 0.f;
    if (ai != INT_MAX && v > 0.f) {
      float4 bb = ((const float4*)pb_b)[ai];
      float c = ciou_pair(x1, y1, x2, y2, atan_t, bb.x, bb.y, bb.z, bb.w,
                          atan_wh(bb.x, bb.y, bb.z, bb.w));
      io = fminf(fmaxf(c, 0.f), 1.f);
    } else { ai = -1; v = 0.f; }
    size_t o = (size_t)row * KTOP + k;
    top_val[o] = v; top_idx[o] = ai; top_iou[o] = io;
  }
}

// ---- K2: one wave per entry: dedup + resolve + per-entry loss terms ------
__global__ __launch_bounds__(256) void k_resolve(
    const float* __restrict__ target, const float* __restrict__ pcls,
    const float* __restrict__ pbox, const float* __restrict__ anchors,
    const float* __restrict__ top_val, const int* __restrict__ top_idx,
    const float* __restrict__ top_iou,
    float* __restrict__ as_tm, float* __restrict__ as_x,
    float* __restrict__ as_cio, int* __restrict__ as_u,
    unsigned* __restrict__ mtg, unsigned* __restrict__ mig)
{
  int gid = blockIdx.x * 256 + threadIdx.x;
  int entry = gid >> 6;            // one 64-lane wave per entry
  int lane = threadIdx.x & 63;
  int b = entry / NE;
  int el = entry - b * NE;

  const float* bv = top_val + (size_t)b * NE;
  const int* bix = top_idx + (size_t)b * NE;
  float v = bv[el];
  int a = bix[el];

  bool dead = (v <= 0.f);
  int cnt = 0, first = NE;
  if (!dead) {
    // wave-parallel scan of this batch's 640 entries (L2-hot, coalesced)
    for (int s = lane; s < NE; s += 64) {
      float v2 = bv[s]; int a2 = bix[s];
      if (v2 > 0.f && a2 == a) { cnt++; if (s < first) first = s; }
    }
    for (int off = 32; off > 0; off >>= 1) {
      cnt += __shfl_xor(cnt, off);
      int of = __shfl_xor(first, off);
      first = of < first ? of : first;
    }
    if (first != el) dead = true;   // not the representative entry
  }
  if (dead) {
    if (lane == 0) { as_tm[entry] = 0.f; as_x[entry] = 0.f;
                     as_cio[entry] = 0.f; as_u[entry] = 0; }
    return;
  }

  const float* pb = pbox + ((size_t)b * NA + a) * 4;
  int u; float tm = -1.f, io;
  if (cnt == 1) {
    u = el / KTOP; tm = v; io = top_iou[entry];
  } else {
    // duplicate: argmax over the 64 targets of clipped ciou, one per lane
    const float* tg = target + (size_t)(b * NT + lane) * 5;
    float tx1 = tg[1], ty1 = tg[2], tx2 = tg[3], ty2 = tg[4];
    float ta = atan_wh(tx1, ty1, tx2, ty2);
    float bx1 = pb[0], by1 = pb[1], bx2 = pb[2], by2 = pb[3];
    float pa = atan_wh(bx1, by1, bx2, by2);
    float c = ciou_pair(tx1, ty1, tx2, ty2, ta, bx1, by1, bx2, by2, pa);
    float cc = fminf(fmaxf(c, 0.f), 1.f);
    float best = cc; int bu = lane;
    for (int off = 32; off > 0; off >>= 1) {
      float ob = __shfl_xor(best, off);
      int ou = __shfl_xor(bu, off);
      if (ob > best || (ob == best && ou < bu)) { best = ob; bu = ou; }
    }
    u = bu; io = best;               // lowest-t tie-break == jnp.argmax
  }

  if (lane == 0) {
    const float* tgu = target + (size_t)(b * NT + u) * 5;
    float ux1 = tgu[1], uy1 = tgu[2], ux2 = tgu[3], uy2 = tgu[4];
    int cu = (int)tgu[0]; cu = cu < 0 ? 0 : (cu > NC - 1 ? NC - 1 : cu);
    float x = pcls[((size_t)b * NA + a) * NC + cu];
    if (cnt != 1) {
      float2 an = ((const float2*)anchors)[a];
      float gm = (ux1 < an.x && an.x < ux2 && uy1 < an.y && an.y < uy2) ? 1.f : 0.f;
      float i2 = io * io; float i6 = i2 * i2 * i2;
      float sig = 1.f / (1.f + expf(-x));
      tm = gm * i6 * sqrtf(sig);
    }
    float bx1 = pb[0], by1 = pb[1], bx2 = pb[2], by2 = pb[3];
    float c = ciou_pair(ux1, uy1, ux2, uy2, atan_wh(ux1, uy1, ux2, uy2),
                        bx1, by1, bx2, by2, atan_wh(bx1, by1, bx2, by2));
    as_tm[entry] = tm; as_x[entry] = x; as_cio[entry] = 1.f - c; as_u[entry] = u;
    atomicMax(&mtg[b * NT + u], __float_as_uint(tm));  // non-neg: uint order == float order
    atomicMax(&mig[b * NT + u], __float_as_uint(io));
  }
}

// ---- K3: per-batch fixed-order reduction of precomputed terms ------------
__global__ __launch_bounds__(256) void k_sums(
    const float* __restrict__ as_tm, const float* __restrict__ as_x,
    const float* __restrict__ as_cio, const int* __restrict__ as_u,
    const unsigned* __restrict__ mtg, const unsigned* __restrict__ mig,
    double* __restrict__ part /* [NB][3] */)
{
  int b = blockIdx.x;
  int tid = threadIdx.x;
  __shared__ double red[256];

  double s1 = 0.0, s2 = 0.0, s3 = 0.0;
  for (int e = tid; e < NE; e += 256) {
    size_t o = (size_t)b * NE + e;
    float tm = as_tm[o];
    int u = as_u[o];
    float maxt = __uint_as_float(mtg[b * NT + u]);
    float maxi = __uint_as_float(mig[b * NT + u]);
    float nrm = tm / (maxt + 1e-9f) * maxi;   // exact 0 for dead entries
    s1 += (double)nrm;
    s2 += (double)as_x[o] * (double)nrm;
    s3 += (double)(as_cio[o] * nrm);
  }
  red[tid] = s1; __syncthreads();
  for (int off = 128; off > 0; off >>= 1) {
    if (tid < off) red[tid] += red[tid + off];
    __syncthreads();
  }
  if (tid == 0) part[b * 3 + 0] = red[0];
  __syncthreads();
  red[tid] = s2; __syncthreads();
  for (int off = 128; off > 0; off >>= 1) {
    if (tid < off) red[tid] += red[tid + off];
    __syncthreads();
  }
  if (tid == 0) part[b * 3 + 1] = red[0];
  __syncthreads();
  red[tid] = s3; __syncthreads();
  for (int off = 128; off > 0; off >>= 1) {
    if (tid < off) red[tid] += red[tid + off];
    __syncthreads();
  }
  if (tid == 0) part[b * 3 + 2] = red[0];
}

// ---- K4: softplus sum over all of predict_cls (memory-bound, 86 MB) ------
#define BCE_BLOCKS 2048
__global__ __launch_bounds__(256) void k_bce(const float* __restrict__ pcls,
                                             double* __restrict__ part) {
  const float4* p4 = (const float4*)pcls;
  const int n4 = NB * NA * NC / 4;  // 5,376,000
  double acc = 0.0;
  for (int i = blockIdx.x * 256 + threadIdx.x; i < n4; i += BCE_BLOCKS * 256) {
    float4 v = p4[i];
    acc += (double)(softplus_f(v.x) + softplus_f(v.y) +
                    softplus_f(v.z) + softplus_f(v.w));
  }
  __shared__ double red[256];
  red[threadIdx.x] = acc; __syncthreads();
  for (int off = 128; off > 0; off >>= 1) {
    if (threadIdx.x < off) red[threadIdx.x] += red[threadIdx.x + off];
    __syncthreads();
  }
  if (threadIdx.x == 0) part[blockIdx.x] = red[0];
}

// ---- K5: combine everything ----------------------------------------------
__global__ __launch_bounds__(256) void k_final(const double* __restrict__ bce_part,
                                               const double* __restrict__ k2_part,
                                               float* __restrict__ out) {
  __shared__ double red[256];
  int tid = threadIdx.x;
  double s = 0.0;
  for (int i = tid; i < BCE_BLOCKS; i += 256) s += bce_part[i];
  red[tid] = s; __syncthreads();
  for (int off = 128; off > 0; off >>= 1) {
    if (tid < off) red[tid] += red[tid + off];
    __syncthreads();
  }
  double s4 = red[0]; __syncthreads();

  red[tid] = (tid < NB) ? k2_part[3 * tid + 0] : 0.0; __syncthreads();
  for (int off = 128; off > 0; off >>= 1) {
    if (tid < off) red[tid] += red[tid + off];
    __syncthreads();
  }
  double s1 = red[0]; __syncthreads();

  red[tid] = (tid < NB) ? k2_part[3 * tid + 1] : 0.0; __syncthreads();
  for (int off = 128; off > 0; off >>= 1) {
    if (tid < off) red[tid] += red[tid + off];
    __syncthreads();
  }
  double s2 = red[0]; __syncthreads();

  red[tid] = (tid < NB) ? k2_part[3 * tid + 2] : 0.0; __syncthreads();
  for (int off = 128; off > 0; off >>= 1) {
    if (tid < off) red[tid] += red[tid + off];
    __syncthreads();
  }
  double s3 = red[0];

  if (tid == 0) {
    double cn = fmax(s1, 1.0);
    out[0] = (float)(s3 / cn);         // loss_iou
    out[1] = (float)((s4 - s2) / cn);  // loss_cls
  }
}

extern "C" void kernel_launch(void* const* d_in, const int* in_sizes, int n_in,
                              void* d_out, int out_size, void* d_ws, size_t ws_size,
                              hipStream_t stream) {
  const float* target  = (const float*)d_in[0];  // [32,64,5]
  const float* pcls    = (const float*)d_in[1];  // [32,8400,80]
  const float* pbox    = (const float*)d_in[2];  // [32,8400,4]
  const float* anchors = (const float*)d_in[3];  // [8400,2]
  float* out = (float*)d_out;

  char* ws = (char*)d_ws;
  float*    top_val = (float*)ws;                    // 20480 f  =  81,920 B
  int*      top_idx = (int*)(ws + 81920);            //             81,920 B
  float*    top_iou = (float*)(ws + 163840);         //             81,920 B
  float*    as_tm   = (float*)(ws + 245760);         //             81,920 B
  float*    as_x    = (float*)(ws + 327680);         //             81,920 B
  float*    as_cio  = (float*)(ws + 409600);         //             81,920 B
  int*      as_u    = (int*)(ws + 491520);           //             81,920 B
  unsigned* mtg     = (unsigned*)(ws + 573440);      // 2048 u   =   8,192 B
  unsigned* mig     = (unsigned*)(ws + 581632);      //              8,192 B
  double*   k2_part = (double*)(ws + 589824);        // 96 d     =     768 B
  double*   k3_part = (double*)(ws + 590592);        // 2048 d   =  16,384 B
  // total ws use: 606,976 B

  k_topk<<<NB * NT, 256, 0, stream>>>(target, pcls, pbox, anchors,
                                      top_val, top_idx, top_iou, mtg, mig);
  k_resolve<<<(NB * NE * 64) / 256, 256, 0, stream>>>(
      target, pcls, pbox, anchors, top_val, top_idx, top_iou,
      as_tm, as_x, as_cio, as_u, mtg, mig);
  k_sums<<<NB, 256, 0, stream>>>(as_tm, as_x, as_cio, as_u, mtg, mig, k2_part);
  k_bce<<<BCE_BLOCKS, 256, 0, stream>>>(pcls, k3_part);
  k_final<<<1, 256, 0, stream>>>(k3_part, k2_part, out);
}

// Round 7
// 95.976 us; speedup vs baseline: 4.3572x; 1.4790x over previous
//
#include <hip/hip_runtime.h>
#include <climits>
#include <cmath>

// YOLOv9 loss forward.  B=32 T=64 A=8400 C=80.
// Pipeline: k_topk (per (b,t) row top-10 via register/wave selection) ->
// k_resolve (one wave per candidate entry) -> k_sums -> k_bce -> k_final.
// All cross-thread combines are order-invariant atomics or fixed-order
// trees -> deterministic across graph replays.

#define NB 32
#define NT 64
#define NA 8400
#define NC 80
#define KTOP 10
#define NE (NT * KTOP)   // 640 entries per batch
#define CAP 1024         // max compacted candidates (worst case ~650)
#define EPSF 1e-7f
#define INV_PI2 0.40528473456935108577f  // 4/pi^2
#define LOG2E_F 1.44269504088896340736f
#define LN2_F   0.69314718055994530942f

__device__ __forceinline__ float atan_wh(float x1, float y1, float x2, float y2) {
  return atanf((x2 - x1) / (y2 - y1 + EPSF));
}

__device__ __forceinline__ float ciou_pair(
    float ax1, float ay1, float ax2, float ay2, float atA,
    float bx1, float by1, float bx2, float by2, float atB)
{
  float xi1 = fmaxf(ax1, bx1), yi1 = fmaxf(ay1, by1);
  float xi2 = fminf(ax2, bx2), yi2 = fminf(ay2, by2);
  float inter = fmaxf(xi2 - xi1, 0.f) * fmaxf(yi2 - yi1, 0.f);
  float a1 = (ax2 - ax1) * (ay2 - ay1);
  float a2 = (bx2 - bx1) * (by2 - by1);
  float iou = inter / (a1 + a2 - inter + EPSF);
  float dcx = (ax2 + ax1) * 0.5f - (bx2 + bx1) * 0.5f;
  float dcy = (ay2 + ay1) * 0.5f - (by2 + by1) * 0.5f;
  float cent = dcx * dcx + dcy * dcy;
  float cw = fmaxf(ax2, bx2) - fminf(ax1, bx1);
  float ch = fmaxf(ay2, by2) - fminf(ay1, by1);
  float diag = cw * cw + ch * ch + EPSF;
  float dv = atA - atB;
  float v = INV_PI2 * dv * dv;
  float alpha = v / (v - iou + 1.f + EPSF);
  return iou - cent / diag - alpha * v;
}

// Fast softplus on the native transcendental pipe.
// e = exp(-|x|) in (0,1] so log1p(e) = ln2*log2(1+e) with 1+e in (1,2]:
// well-conditioned, no log1p machinery needed.  ~2e-7 abs error/element.
__device__ __forceinline__ float softplus_fast(float x) {
  float e = exp2f(-LOG2E_F * fabsf(x));     // v_exp_f32
  float l = __log2f(1.f + e);               // v_log_f32
  return fmaxf(x, 0.f) + LN2_F * l;
}

// ---- K1: per (b,t) row: compact grid-passing anchors, top-10 in regs -----
__global__ __launch_bounds__(256) void k_topk(
    const float* __restrict__ target,   // [B,T,5]
    const float* __restrict__ pcls,     // [B,A,C]
    const float* __restrict__ pbox,     // [B,A,4]
    const float* __restrict__ anchors,  // [A,2]
    float* __restrict__ top_val, int* __restrict__ top_idx,
    float* __restrict__ top_iou,
    unsigned* __restrict__ mtg, unsigned* __restrict__ mig)
{
  int row = blockIdx.x;            // b*NT + t   (grid is exactly NB*NT)
  int tid = threadIdx.x;
  if (tid == 0) { mtg[row] = 0u; mig[row] = 0u; }  // zero max tables
  int b = row >> 6;
  const float* tg = target + (size_t)row * 5;
  float tcf = tg[0];
  float x1 = tg[1], y1 = tg[2], x2 = tg[3], y2 = tg[4];
  int tc = (int)tcf; tc = tc < 0 ? 0 : (tc > NC - 1 ? NC - 1 : tc);
  float atan_t = atan_wh(x1, y1, x2, y2);

  __shared__ int s_n;
  __shared__ float s_val[CAP];
  __shared__ int s_idx[CAP];
  __shared__ float xw_v[4];  __shared__ int xw_a[4];
  __shared__ float w_val[KTOP]; __shared__ int w_idx[KTOP];
  if (tid == 0) s_n = 0;
  __syncthreads();

  const float* pb_b = pbox + (size_t)b * NA * 4;
  const float* pc_b = pcls + (size_t)b * NA * NC;
  const float4* an4 = (const float4*)anchors;   // 2 anchors per float4

  for (int p = tid; p < NA / 2; p += 256) {
    float4 aa = an4[p];
#pragma unroll
    for (int h = 0; h < 2; h++) {
      int a = 2 * p + h;
      float anx = h ? aa.z : aa.x;
      float any_ = h ? aa.w : aa.y;
      if (x1 < anx && anx < x2 && y1 < any_ && any_ < y2) {
        float4 bb = ((const float4*)pb_b)[a];
        float c = ciou_pair(x1, y1, x2, y2, atan_t, bb.x, bb.y, bb.z, bb.w,
                            atan_wh(bb.x, bb.y, bb.z, bb.w));
        float io = fminf(fmaxf(c, 0.f), 1.f);
        float i2 = io * io;
        float i6 = i2 * i2 * i2;
        float s = pc_b[(size_t)a * NC + tc];
        float sig = 1.f / (1.f + expf(-s));
        float tm = i6 * sqrtf(sig);
        int slot = atomicAdd(&s_n, 1);
        if (slot < CAP) { s_val[slot] = tm; s_idx[slot] = a; }
      }
    }
  }
  __syncthreads();
  int n = s_n; if (n > CAP) n = CAP;

  // load candidates into 4 static register slots per thread
  float v0 = -1.f, v1 = -1.f, v2 = -1.f, v3 = -1.f;
  int a0 = INT_MAX, a1 = INT_MAX, a2 = INT_MAX, a3 = INT_MAX;
  if (tid < n)       { v0 = s_val[tid];       a0 = s_idx[tid]; }
  if (tid + 256 < n) { v1 = s_val[tid + 256]; a1 = s_idx[tid + 256]; }
  if (tid + 512 < n) { v2 = s_val[tid + 512]; a2 = s_idx[tid + 512]; }
  if (tid + 768 < n) { v3 = s_val[tid + 768]; a3 = s_idx[tid + 768]; }

  // 10 rounds: local 4-max -> wave butterfly -> 4-wave LDS merge -> kill.
  // Tie-break everywhere: (value desc, anchor index asc) == lax.top_k.
  for (int k = 0; k < KTOP; k++) {
    float bv = v0; int ba = a0;
    if (v1 > bv || (v1 == bv && a1 < ba)) { bv = v1; ba = a1; }
    if (v2 > bv || (v2 == bv && a2 < ba)) { bv = v2; ba = a2; }
    if (v3 > bv || (v3 == bv && a3 < ba)) { bv = v3; ba = a3; }
#pragma unroll
    for (int off = 32; off > 0; off >>= 1) {
      float ov = __shfl_xor(bv, off); int oa = __shfl_xor(ba, off);
      if (ov > bv || (ov == bv && oa < ba)) { bv = ov; ba = oa; }
    }
    if ((tid & 63) == 0) { xw_v[tid >> 6] = bv; xw_a[tid >> 6] = ba; }
    __syncthreads();
    float fv = xw_v[0]; int fa = xw_a[0];
    { float ov = xw_v[1]; int oa = xw_a[1];
      if (ov > fv || (ov == fv && oa < fa)) { fv = ov; fa = oa; } }
    { float ov = xw_v[2]; int oa = xw_a[2];
      if (ov > fv || (ov == fv && oa < fa)) { fv = ov; fa = oa; } }
    { float ov = xw_v[3]; int oa = xw_a[3];
      if (ov > fv || (ov == fv && oa < fa)) { fv = ov; fa = oa; } }
    if (tid == 0) { w_val[k] = fv; w_idx[k] = fa; }
    // kill winner (anchor indices unique; sentinel-kill is a no-op)
    if (a0 == fa) { v0 = -1.f; a0 = INT_MAX; }
    if (a1 == fa) { v1 = -1.f; a1 = INT_MAX; }
    if (a2 == fa) { v2 = -1.f; a2 = INT_MAX; }
    if (a3 == fa) { v3 = -1.f; a3 = INT_MAX; }
    __syncthreads();
  }

  // write winners; recompute clipped ciou for each (10 per block, trivial)
  if (tid < KTOP) {
    int k = tid;
    int ai = w_idx[k]; float v = w_val[k];
    float io = 0.f;
    if (ai != INT_MAX && v > 0.f) {
      float4 bb = ((const float4*)pb_b)[ai];
      float c = ciou_pair(x1, y1, x2, y2, atan_t, bb.x, bb.y, bb.z, bb.w,
                          atan_wh(bb.x, bb.y, bb.z, bb.w));
      io = fminf(fmaxf(c, 0.f), 1.f);
    } else { ai = -1; v = 0.f; }
    size_t o = (size_t)row * KTOP + k;
    top_val[o] = v; top_idx[o] = ai; top_iou[o] = io;
  }
}

// ---- K2: one wave per entry: dedup + resolve + per-entry loss terms ------
__global__ __launch_bounds__(256) void k_resolve(
    const float* __restrict__ target, const float* __restrict__ pcls,
    const float* __restrict__ pbox, const float* __restrict__ anchors,
    const float* __restrict__ top_val, const int* __restrict__ top_idx,
    const float* __restrict__ top_iou,
    float* __restrict__ as_tm, float* __restrict__ as_x,
    float* __restrict__ as_cio, int* __restrict__ as_u,
    unsigned* __restrict__ mtg, unsigned* __restrict__ mig)
{
  int gid = blockIdx.x * 256 + threadIdx.x;
  int entry = gid >> 6;            // one 64-lane wave per entry
  int lane = threadIdx.x & 63;
  int b = entry / NE;
  int el = entry - b * NE;

  const float* bv = top_val + (size_t)b * NE;
  const int* bix = top_idx + (size_t)b * NE;
  float v = bv[el];
  int a = bix[el];

  bool dead = (v <= 0.f);
  int cnt = 0, first = NE;
  if (!dead) {
    // wave-parallel scan of this batch's 640 entries (L2-hot, coalesced)
    for (int s = lane; s < NE; s += 64) {
      float v2 = bv[s]; int a2 = bix[s];
      if (v2 > 0.f && a2 == a) { cnt++; if (s < first) first = s; }
    }
    for (int off = 32; off > 0; off >>= 1) {
      cnt += __shfl_xor(cnt, off);
      int of = __shfl_xor(first, off);
      first = of < first ? of : first;
    }
    if (first != el) dead = true;   // not the representative entry
  }
  if (dead) {
    if (lane == 0) { as_tm[entry] = 0.f; as_x[entry] = 0.f;
                     as_cio[entry] = 0.f; as_u[entry] = 0; }
    return;
  }

  const float* pb = pbox + ((size_t)b * NA + a) * 4;
  int u; float tm = -1.f, io;
  if (cnt == 1) {
    u = el / KTOP; tm = v; io = top_iou[entry];
  } else {
    // duplicate: argmax over the 64 targets of clipped ciou, one per lane
    const float* tg = target + (size_t)(b * NT + lane) * 5;
    float tx1 = tg[1], ty1 = tg[2], tx2 = tg[3], ty2 = tg[4];
    float ta = atan_wh(tx1, ty1, tx2, ty2);
    float bx1 = pb[0], by1 = pb[1], bx2 = pb[2], by2 = pb[3];
    float pa = atan_wh(bx1, by1, bx2, by2);
    float c = ciou_pair(tx1, ty1, tx2, ty2, ta, bx1, by1, bx2, by2, pa);
    float cc = fminf(fmaxf(c, 0.f), 1.f);
    float best = cc; int bu = lane;
    for (int off = 32; off > 0; off >>= 1) {
      float ob = __shfl_xor(best, off);
      int ou = __shfl_xor(bu, off);
      if (ob > best || (ob == best && ou < bu)) { best = ob; bu = ou; }
    }
    u = bu; io = best;               // lowest-t tie-break == jnp.argmax
  }

  if (lane == 0) {
    const float* tgu = target + (size_t)(b * NT + u) * 5;
    float ux1 = tgu[1], uy1 = tgu[2], ux2 = tgu[3], uy2 = tgu[4];
    int cu = (int)tgu[0]; cu = cu < 0 ? 0 : (cu > NC - 1 ? NC - 1 : cu);
    float x = pcls[((size_t)b * NA + a) * NC + cu];
    if (cnt != 1) {
      float2 an = ((const float2*)anchors)[a];
      float gm = (ux1 < an.x && an.x < ux2 && uy1 < an.y && an.y < uy2) ? 1.f : 0.f;
      float i2 = io * io; float i6 = i2 * i2 * i2;
      float sig = 1.f / (1.f + expf(-x));
      tm = gm * i6 * sqrtf(sig);
    }
    float bx1 = pb[0], by1 = pb[1], bx2 = pb[2], by2 = pb[3];
    float c = ciou_pair(ux1, uy1, ux2, uy2, atan_wh(ux1, uy1, ux2, uy2),
                        bx1, by1, bx2, by2, atan_wh(bx1, by1, bx2, by2));
    as_tm[entry] = tm; as_x[entry] = x; as_cio[entry] = 1.f - c; as_u[entry] = u;
    atomicMax(&mtg[b * NT + u], __float_as_uint(tm));  // non-neg: uint order == float order
    atomicMax(&mig[b * NT + u], __float_as_uint(io));
  }
}

// ---- K3: per-batch fixed-order reduction of precomputed terms ------------
__global__ __launch_bounds__(256) void k_sums(
    const float* __restrict__ as_tm, const float* __restrict__ as_x,
    const float* __restrict__ as_cio, const int* __restrict__ as_u,
    const unsigned* __restrict__ mtg, const unsigned* __restrict__ mig,
    double* __restrict__ part /* [NB][3] */)
{
  int b = blockIdx.x;
  int tid = threadIdx.x;
  __shared__ double red[256];

  double s1 = 0.0, s2 = 0.0, s3 = 0.0;
  for (int e = tid; e < NE; e += 256) {
    size_t o = (size_t)b * NE + e;
    float tm = as_tm[o];
    int u = as_u[o];
    float maxt = __uint_as_float(mtg[b * NT + u]);
    float maxi = __uint_as_float(mig[b * NT + u]);
    float nrm = tm / (maxt + 1e-9f) * maxi;   // exact 0 for dead entries
    s1 += (double)nrm;
    s2 += (double)as_x[o] * (double)nrm;
    s3 += (double)(as_cio[o] * nrm);
  }
  red[tid] = s1; __syncthreads();
  for (int off = 128; off > 0; off >>= 1) {
    if (tid < off) red[tid] += red[tid + off];
    __syncthreads();
  }
  if (tid == 0) part[b * 3 + 0] = red[0];
  __syncthreads();
  red[tid] = s2; __syncthreads();
  for (int off = 128; off > 0; off >>= 1) {
    if (tid < off) red[tid] += red[tid + off];
    __syncthreads();
  }
  if (tid == 0) part[b * 3 + 1] = red[0];
  __syncthreads();
  red[tid] = s3; __syncthreads();
  for (int off = 128; off > 0; off >>= 1) {
    if (tid < off) red[tid] += red[tid + off];
    __syncthreads();
  }
  if (tid == 0) part[b * 3 + 2] = red[0];
}

// ---- K4: softplus sum over all of predict_cls ----------------------------
#define BCE_BLOCKS 2048
__global__ __launch_bounds__(256) void k_bce(const float* __restrict__ pcls,
                                             double* __restrict__ part) {
  const float4* p4 = (const float4*)pcls;
  const int n4 = NB * NA * NC / 4;  // 5,376,000
  double acc = 0.0;
  for (int i = blockIdx.x * 256 + threadIdx.x; i < n4; i += BCE_BLOCKS * 256) {
    float4 v = p4[i];
    float p = (softplus_fast(v.x) + softplus_fast(v.y)) +
              (softplus_fast(v.z) + softplus_fast(v.w));
    acc += (double)p;
  }
  __shared__ double red[256];
  red[threadIdx.x] = acc; __syncthreads();
  for (int off = 128; off > 0; off >>= 1) {
    if (threadIdx.x < off) red[threadIdx.x] += red[threadIdx.x + off];
    __syncthreads();
  }
  if (threadIdx.x == 0) part[blockIdx.x] = red[0];
}

// ---- K5: combine everything ----------------------------------------------
__global__ __launch_bounds__(256) void k_final(const double* __restrict__ bce_part,
                                               const double* __restrict__ k2_part,
                                               float* __restrict__ out) {
  __shared__ double red[256];
  int tid = threadIdx.x;
  double s = 0.0;
  for (int i = tid; i < BCE_BLOCKS; i += 256) s += bce_part[i];
  red[tid] = s; __syncthreads();
  for (int off = 128; off > 0; off >>= 1) {
    if (tid < off) red[tid] += red[tid + off];
    __syncthreads();
  }
  double s4 = red[0]; __syncthreads();

  red[tid] = (tid < NB) ? k2_part[3 * tid + 0] : 0.0; __syncthreads();
  for (int off = 128; off > 0; off >>= 1) {
    if (tid < off) red[tid] += red[tid + off];
    __syncthreads();
  }
  double s1 = red[0]; __syncthreads();

  red[tid] = (tid < NB) ? k2_part[3 * tid + 1] : 0.0; __syncthreads();
  for (int off = 128; off > 0; off >>= 1) {
    if (tid < off) red[tid] += red[tid + off];
    __syncthreads();
  }
  double s2 = red[0]; __syncthreads();

  red[tid] = (tid < NB) ? k2_part[3 * tid + 2] : 0.0; __syncthreads();
  for (int off = 128; off > 0; off >>= 1) {
    if (tid < off) red[tid] += red[tid + off];
    __syncthreads();
  }
  double s3 = red[0];

  if (tid == 0) {
    double cn = fmax(s1, 1.0);
    out[0] = (float)(s3 / cn);         // loss_iou
    out[1] = (float)((s4 - s2) / cn);  // loss_cls
  }
}

extern "C" void kernel_launch(void* const* d_in, const int* in_sizes, int n_in,
                              void* d_out, int out_size, void* d_ws, size_t ws_size,
                              hipStream_t stream) {
  const float* target  = (const float*)d_in[0];  // [32,64,5]
  const float* pcls    = (const float*)d_in[1];  // [32,8400,80]
  const float* pbox    = (const float*)d_in[2];  // [32,8400,4]
  const float* anchors = (const float*)d_in[3];  // [8400,2]
  float* out = (float*)d_out;

  char* ws = (char*)d_ws;
  float*    top_val = (float*)ws;                    // 20480 f  =  81,920 B
  int*      top_idx = (int*)(ws + 81920);            //             81,920 B
  float*    top_iou = (float*)(ws + 163840);         //             81,920 B
  float*    as_tm   = (float*)(ws + 245760);         //             81,920 B
  float*    as_x    = (float*)(ws + 327680);         //             81,920 B
  float*    as_cio  = (float*)(ws + 409600);         //             81,920 B
  int*      as_u    = (int*)(ws + 491520);           //             81,920 B
  unsigned* mtg     = (unsigned*)(ws + 573440);      // 2048 u   =   8,192 B
  unsigned* mig     = (unsigned*)(ws + 581632);      //              8,192 B
  double*   k2_part = (double*)(ws + 589824);        // 96 d     =     768 B
  double*   k3_part = (double*)(ws + 590592);        // 2048 d   =  16,384 B
  // total ws use: 606,976 B

  k_topk<<<NB * NT, 256, 0, stream>>>(target, pcls, pbox, anchors,
                                      top_val, top_idx, top_iou, mtg, mig);
  k_resolve<<<(NB * NE * 64) / 256, 256, 0, stream>>>(
      target, pcls, pbox, anchors, top_val, top_idx, top_iou,
      as_tm, as_x, as_cio, as_u, mtg, mig);
  k_sums<<<NB, 256, 0, stream>>>(as_tm, as_x, as_cio, as_u, mtg, mig, k2_part);
  k_bce<<<BCE_BLOCKS, 256, 0, stream>>>(pcls, k3_part);
  k_final<<<1, 256, 0, stream>>>(k3_part, k2_part, out);
}

// Round 8
// 80.059 us; speedup vs baseline: 5.2235x; 1.1988x over previous
//
#include <hip/hip_runtime.h>
#include <climits>
#include <cmath>

// YOLOv9 loss forward.  B=32 T=64 A=8400 C=80.
// Pipeline: k_topk (analytic candidate enumeration + register/wave top-10)
// -> k_resolve (one wave per candidate entry) -> k_bce_sums (softplus sum
// fused with per-batch term reduction) -> k_final.
// All cross-thread combines are order-invariant atomics or fixed-order
// trees -> deterministic across graph replays.

#define NB 32
#define NT 64
#define NA 8400
#define NC 80
#define KTOP 10
#define NE (NT * KTOP)   // 640 entries per batch
#define CAP 1024         // max compacted candidates (worst case ~650)
#define EPSF 1e-7f
#define INV_PI2 0.40528473456935108577f  // 4/pi^2
#define LOG2E_F 1.44269504088896340736f
#define LN2_F   0.69314718055994530942f

__device__ __forceinline__ float atan_wh(float x1, float y1, float x2, float y2) {
  return atanf((x2 - x1) / (y2 - y1 + EPSF));
}

__device__ __forceinline__ float ciou_pair(
    float ax1, float ay1, float ax2, float ay2, float atA,
    float bx1, float by1, float bx2, float by2, float atB)
{
  float xi1 = fmaxf(ax1, bx1), yi1 = fmaxf(ay1, by1);
  float xi2 = fminf(ax2, bx2), yi2 = fminf(ay2, by2);
  float inter = fmaxf(xi2 - xi1, 0.f) * fmaxf(yi2 - yi1, 0.f);
  float a1 = (ax2 - ax1) * (ay2 - ay1);
  float a2 = (bx2 - bx1) * (by2 - by1);
  float iou = inter / (a1 + a2 - inter + EPSF);
  float dcx = (ax2 + ax1) * 0.5f - (bx2 + bx1) * 0.5f;
  float dcy = (ay2 + ay1) * 0.5f - (by2 + by1) * 0.5f;
  float cent = dcx * dcx + dcy * dcy;
  float cw = fmaxf(ax2, bx2) - fminf(ax1, bx1);
  float ch = fmaxf(ay2, by2) - fminf(ay1, by1);
  float diag = cw * cw + ch * ch + EPSF;
  float dv = atA - atB;
  float v = INV_PI2 * dv * dv;
  float alpha = v / (v - iou + 1.f + EPSF);
  return iou - cent / diag - alpha * v;
}

// Fast softplus on the native transcendental pipe (verified absmax 0.0 r7).
__device__ __forceinline__ float softplus_fast(float x) {
  float e = exp2f(-LOG2E_F * fabsf(x));     // v_exp_f32
  float l = __log2f(1.f + e);               // v_log_f32
  return fmaxf(x, 0.f) + LN2_F * l;
}

// ---- K1: per (b,t) row: enumerate passing anchors analytically, top-10 ---
// Anchors are 3 meshgrids: level l has n_l x n_l cells at (i+0.5)*s_l,
// s = {8,16,32}, n = {80,40,20}, base = {0,6400,8000}; a = base + iy*n + ix.
// (ix+0.5)*s is an exact small integer in f32 == the anchors input values.
__global__ __launch_bounds__(256) void k_topk(
    const float* __restrict__ target,   // [B,T,5]
    const float* __restrict__ pcls,     // [B,A,C]
    const float* __restrict__ pbox,     // [B,A,4]
    float* __restrict__ top_val, int* __restrict__ top_idx,
    float* __restrict__ top_iou,
    unsigned* __restrict__ mtg, unsigned* __restrict__ mig)
{
  int row = blockIdx.x;            // b*NT + t   (grid is exactly NB*NT)
  int tid = threadIdx.x;
  if (tid == 0) { mtg[row] = 0u; mig[row] = 0u; }  // zero max tables
  int b = row >> 6;
  const float* tg = target + (size_t)row * 5;
  float tcf = tg[0];
  float x1 = tg[1], y1 = tg[2], x2 = tg[3], y2 = tg[4];
  int tc = (int)tcf; tc = tc < 0 ? 0 : (tc > NC - 1 ? NC - 1 : tc);
  float atan_t = atan_wh(x1, y1, x2, y2);

  __shared__ int s_n;
  __shared__ float s_val[CAP];
  __shared__ int s_idx[CAP];
  __shared__ float xw_v[4];  __shared__ int xw_a[4];
  __shared__ float w_val[KTOP]; __shared__ int w_idx[KTOP];
  if (tid == 0) s_n = 0;
  __syncthreads();

  const float* pb_b = pbox + (size_t)b * NA * 4;
  const float* pc_b = pcls + (size_t)b * NA * NC;

  // three static per-level loops (no runtime-indexed arrays -> registers)
#define LEVEL_LOOP(S, N, BASE)                                              \
  {                                                                         \
    const float s = (float)(S);                                             \
    /* i in (x/s - 0.5) open interval; widen 1 each side, exact test below */\
    int ix0 = (int)floorf(x1 / s - 0.5f); ix0 = ix0 < 0 ? 0 : ix0;          \
    int ix1 = (int)ceilf (x2 / s - 0.5f); ix1 = ix1 > (N)-1 ? (N)-1 : ix1;  \
    int iy0 = (int)floorf(y1 / s - 0.5f); iy0 = iy0 < 0 ? 0 : iy0;          \
    int iy1 = (int)ceilf (y2 / s - 0.5f); iy1 = iy1 > (N)-1 ? (N)-1 : iy1;  \
    int w = ix1 - ix0 + 1; w = w < 0 ? 0 : w;                               \
    int h = iy1 - iy0 + 1; h = h < 0 ? 0 : h;                               \
    int cnt = w * h;                                                        \
    for (int k = tid; k < cnt; k += 256) {                                  \
      int ix = ix0 + k % w;                                                 \
      int iy = iy0 + k / w;                                                 \
      float anx = (ix + 0.5f) * s;                                          \
      float any_ = (iy + 0.5f) * s;                                         \
      if (x1 < anx && anx < x2 && y1 < any_ && any_ < y2) {                 \
        int a = (BASE) + iy * (N) + ix;                                     \
        float4 bb = ((const float4*)pb_b)[a];                               \
        float c = ciou_pair(x1, y1, x2, y2, atan_t, bb.x, bb.y, bb.z, bb.w, \
                            atan_wh(bb.x, bb.y, bb.z, bb.w));               \
        float io = fminf(fmaxf(c, 0.f), 1.f);                               \
        float i2 = io * io;                                                 \
        float i6 = i2 * i2 * i2;                                            \
        float sc = pc_b[(size_t)a * NC + tc];                               \
        float sig = 1.f / (1.f + expf(-sc));                                \
        float tm = i6 * sqrtf(sig);                                         \
        int slot = atomicAdd(&s_n, 1);                                      \
        if (slot < CAP) { s_val[slot] = tm; s_idx[slot] = a; }              \
      }                                                                     \
    }                                                                       \
  }
  LEVEL_LOOP(8, 80, 0)
  LEVEL_LOOP(16, 40, 6400)
  LEVEL_LOOP(32, 20, 8000)
#undef LEVEL_LOOP
  __syncthreads();
  int n = s_n; if (n > CAP) n = CAP;

  // load candidates into 4 static register slots per thread
  float v0 = -1.f, v1 = -1.f, v2 = -1.f, v3 = -1.f;
  int a0 = INT_MAX, a1 = INT_MAX, a2 = INT_MAX, a3 = INT_MAX;
  if (tid < n)       { v0 = s_val[tid];       a0 = s_idx[tid]; }
  if (tid + 256 < n) { v1 = s_val[tid + 256]; a1 = s_idx[tid + 256]; }
  if (tid + 512 < n) { v2 = s_val[tid + 512]; a2 = s_idx[tid + 512]; }
  if (tid + 768 < n) { v3 = s_val[tid + 768]; a3 = s_idx[tid + 768]; }

  // 10 rounds: local 4-max -> wave butterfly -> 4-wave LDS merge -> kill.
  // Tie-break everywhere: (value desc, anchor index asc) == lax.top_k.
  for (int k = 0; k < KTOP; k++) {
    float bv = v0; int ba = a0;
    if (v1 > bv || (v1 == bv && a1 < ba)) { bv = v1; ba = a1; }
    if (v2 > bv || (v2 == bv && a2 < ba)) { bv = v2; ba = a2; }
    if (v3 > bv || (v3 == bv && a3 < ba)) { bv = v3; ba = a3; }
#pragma unroll
    for (int off = 32; off > 0; off >>= 1) {
      float ov = __shfl_xor(bv, off); int oa = __shfl_xor(ba, off);
      if (ov > bv || (ov == bv && oa < ba)) { bv = ov; ba = oa; }
    }
    if ((tid & 63) == 0) { xw_v[tid >> 6] = bv; xw_a[tid >> 6] = ba; }
    __syncthreads();
    float fv = xw_v[0]; int fa = xw_a[0];
    { float ov = xw_v[1]; int oa = xw_a[1];
      if (ov > fv || (ov == fv && oa < fa)) { fv = ov; fa = oa; } }
    { float ov = xw_v[2]; int oa = xw_a[2];
      if (ov > fv || (ov == fv && oa < fa)) { fv = ov; fa = oa; } }
    { float ov = xw_v[3]; int oa = xw_a[3];
      if (ov > fv || (ov == fv && oa < fa)) { fv = ov; fa = oa; } }
    if (tid == 0) { w_val[k] = fv; w_idx[k] = fa; }
    // kill winner (anchor indices unique; sentinel-kill is a no-op)
    if (a0 == fa) { v0 = -1.f; a0 = INT_MAX; }
    if (a1 == fa) { v1 = -1.f; a1 = INT_MAX; }
    if (a2 == fa) { v2 = -1.f; a2 = INT_MAX; }
    if (a3 == fa) { v3 = -1.f; a3 = INT_MAX; }
    __syncthreads();
  }

  // write winners; recompute clipped ciou for each (10 per block, trivial)
  if (tid < KTOP) {
    int k = tid;
    int ai = w_idx[k]; float v = w_val[k];
    float io = 0.f;
    if (ai != INT_MAX && v > 0.f) {
      float4 bb = ((const float4*)pb_b)[ai];
      float c = ciou_pair(x1, y1, x2, y2, atan_t, bb.x, bb.y, bb.z, bb.w,
                          atan_wh(bb.x, bb.y, bb.z, bb.w));
      io = fminf(fmaxf(c, 0.f), 1.f);
    } else { ai = -1; v = 0.f; }
    size_t o = (size_t)row * KTOP + k;
    top_val[o] = v; top_idx[o] = ai; top_iou[o] = io;
  }
}

// ---- K2: one wave per entry: dedup + resolve + per-entry loss terms ------
__global__ __launch_bounds__(256) void k_resolve(
    const float* __restrict__ target, const float* __restrict__ pcls,
    const float* __restrict__ pbox, const float* __restrict__ anchors,
    const float* __restrict__ top_val, const int* __restrict__ top_idx,
    const float* __restrict__ top_iou,
    float* __restrict__ as_tm, float* __restrict__ as_x,
    float* __restrict__ as_cio, int* __restrict__ as_u,
    unsigned* __restrict__ mtg, unsigned* __restrict__ mig)
{
  int gid = blockIdx.x * 256 + threadIdx.x;
  int entry = gid >> 6;            // one 64-lane wave per entry
  int lane = threadIdx.x & 63;
  int b = entry / NE;
  int el = entry - b * NE;

  const float* bv = top_val + (size_t)b * NE;
  const int* bix = top_idx + (size_t)b * NE;
  float v = bv[el];
  int a = bix[el];

  bool dead = (v <= 0.f);
  int cnt = 0, first = NE;
  if (!dead) {
    // wave-parallel scan of this batch's 640 entries (L2-hot, coalesced)
    for (int s = lane; s < NE; s += 64) {
      float v2 = bv[s]; int a2 = bix[s];
      if (v2 > 0.f && a2 == a) { cnt++; if (s < first) first = s; }
    }
    for (int off = 32; off > 0; off >>= 1) {
      cnt += __shfl_xor(cnt, off);
      int of = __shfl_xor(first, off);
      first = of < first ? of : first;
    }
    if (first != el) dead = true;   // not the representative entry
  }
  if (dead) {
    if (lane == 0) { as_tm[entry] = 0.f; as_x[entry] = 0.f;
                     as_cio[entry] = 0.f; as_u[entry] = 0; }
    return;
  }

  const float* pb = pbox + ((size_t)b * NA + a) * 4;
  int u; float tm = -1.f, io;
  if (cnt == 1) {
    u = el / KTOP; tm = v; io = top_iou[entry];
  } else {
    // duplicate: argmax over the 64 targets of clipped ciou, one per lane
    const float* tg = target + (size_t)(b * NT + lane) * 5;
    float tx1 = tg[1], ty1 = tg[2], tx2 = tg[3], ty2 = tg[4];
    float ta = atan_wh(tx1, ty1, tx2, ty2);
    float bx1 = pb[0], by1 = pb[1], bx2 = pb[2], by2 = pb[3];
    float pa = atan_wh(bx1, by1, bx2, by2);
    float c = ciou_pair(tx1, ty1, tx2, ty2, ta, bx1, by1, bx2, by2, pa);
    float cc = fminf(fmaxf(c, 0.f), 1.f);
    float best = cc; int bu = lane;
    for (int off = 32; off > 0; off >>= 1) {
      float ob = __shfl_xor(best, off);
      int ou = __shfl_xor(bu, off);
      if (ob > best || (ob == best && ou < bu)) { best = ob; bu = ou; }
    }
    u = bu; io = best;               // lowest-t tie-break == jnp.argmax
  }

  if (lane == 0) {
    const float* tgu = target + (size_t)(b * NT + u) * 5;
    float ux1 = tgu[1], uy1 = tgu[2], ux2 = tgu[3], uy2 = tgu[4];
    int cu = (int)tgu[0]; cu = cu < 0 ? 0 : (cu > NC - 1 ? NC - 1 : cu);
    float x = pcls[((size_t)b * NA + a) * NC + cu];
    if (cnt != 1) {
      float2 an = ((const float2*)anchors)[a];
      float gm = (ux1 < an.x && an.x < ux2 && uy1 < an.y && an.y < uy2) ? 1.f : 0.f;
      float i2 = io * io; float i6 = i2 * i2 * i2;
      float sig = 1.f / (1.f + expf(-x));
      tm = gm * i6 * sqrtf(sig);
    }
    float bx1 = pb[0], by1 = pb[1], bx2 = pb[2], by2 = pb[3];
    float c = ciou_pair(ux1, uy1, ux2, uy2, atan_wh(ux1, uy1, ux2, uy2),
                        bx1, by1, bx2, by2, atan_wh(bx1, by1, bx2, by2));
    as_tm[entry] = tm; as_x[entry] = x; as_cio[entry] = 1.f - c; as_u[entry] = u;
    atomicMax(&mtg[b * NT + u], __float_as_uint(tm));  // non-neg: uint order == float order
    atomicMax(&mig[b * NT + u], __float_as_uint(io));
  }
}

// ---- K3: fused softplus sum (blocks 0..2047) + per-batch sums (2048..) ---
#define BCE_BLOCKS 2048
__global__ __launch_bounds__(256) void k_bce_sums(
    const float* __restrict__ pcls,
    const float* __restrict__ as_tm, const float* __restrict__ as_x,
    const float* __restrict__ as_cio, const int* __restrict__ as_u,
    const unsigned* __restrict__ mtg, const unsigned* __restrict__ mig,
    double* __restrict__ bce_part, double* __restrict__ k2_part)
{
  int tid = threadIdx.x;
  __shared__ double red[256];

  if (blockIdx.x < BCE_BLOCKS) {
    const float4* p4 = (const float4*)pcls;
    const int n4 = NB * NA * NC / 4;  // 5,376,000
    double acc = 0.0;
    for (int i = blockIdx.x * 256 + tid; i < n4; i += BCE_BLOCKS * 256) {
      float4 v = p4[i];
      float p = (softplus_fast(v.x) + softplus_fast(v.y)) +
                (softplus_fast(v.z) + softplus_fast(v.w));
      acc += (double)p;
    }
    red[tid] = acc; __syncthreads();
    for (int off = 128; off > 0; off >>= 1) {
      if (tid < off) red[tid] += red[tid + off];
      __syncthreads();
    }
    if (tid == 0) bce_part[blockIdx.x] = red[0];
    return;
  }

  int b = blockIdx.x - BCE_BLOCKS;
  double s1 = 0.0, s2 = 0.0, s3 = 0.0;
  for (int e = tid; e < NE; e += 256) {
    size_t o = (size_t)b * NE + e;
    float tm = as_tm[o];
    int u = as_u[o];
    float maxt = __uint_as_float(mtg[b * NT + u]);
    float maxi = __uint_as_float(mig[b * NT + u]);
    float nrm = tm / (maxt + 1e-9f) * maxi;   // exact 0 for dead entries
    s1 += (double)nrm;
    s2 += (double)as_x[o] * (double)nrm;
    s3 += (double)(as_cio[o] * nrm);
  }
  red[tid] = s1; __syncthreads();
  for (int off = 128; off > 0; off >>= 1) {
    if (tid < off) red[tid] += red[tid + off];
    __syncthreads();
  }
  if (tid == 0) k2_part[b * 3 + 0] = red[0];
  __syncthreads();
  red[tid] = s2; __syncthreads();
  for (int off = 128; off > 0; off >>= 1) {
    if (tid < off) red[tid] += red[tid + off];
    __syncthreads();
  }
  if (tid == 0) k2_part[b * 3 + 1] = red[0];
  __syncthreads();
  red[tid] = s3; __syncthreads();
  for (int off = 128; off > 0; off >>= 1) {
    if (tid < off) red[tid] += red[tid + off];
    __syncthreads();
  }
  if (tid == 0) k2_part[b * 3 + 2] = red[0];
}

// ---- K4: combine everything ----------------------------------------------
__global__ __launch_bounds__(256) void k_final(const double* __restrict__ bce_part,
                                               const double* __restrict__ k2_part,
                                               float* __restrict__ out) {
  __shared__ double red[256];
  int tid = threadIdx.x;
  double s = 0.0;
  for (int i = tid; i < BCE_BLOCKS; i += 256) s += bce_part[i];
  red[tid] = s; __syncthreads();
  for (int off = 128; off > 0; off >>= 1) {
    if (tid < off) red[tid] += red[tid + off];
    __syncthreads();
  }
  double s4 = red[0]; __syncthreads();

  red[tid] = (tid < NB) ? k2_part[3 * tid + 0] : 0.0; __syncthreads();
  for (int off = 128; off > 0; off >>= 1) {
    if (tid < off) red[tid] += red[tid + off];
    __syncthreads();
  }
  double s1 = red[0]; __syncthreads();

  red[tid] = (tid < NB) ? k2_part[3 * tid + 1] : 0.0; __syncthreads();
  for (int off = 128; off > 0; off >>= 1) {
    if (tid < off) red[tid] += red[tid + off];
    __syncthreads();
  }
  double s2 = red[0]; __syncthreads();

  red[tid] = (tid < NB) ? k2_part[3 * tid + 2] : 0.0; __syncthreads();
  for (int off = 128; off > 0; off >>= 1) {
    if (tid < off) red[tid] += red[tid + off];
    __syncthreads();
  }
  double s3 = red[0];

  if (tid == 0) {
    double cn = fmax(s1, 1.0);
    out[0] = (float)(s3 / cn);         // loss_iou
    out[1] = (float)((s4 - s2) / cn);  // loss_cls
  }
}

extern "C" void kernel_launch(void* const* d_in, const int* in_sizes, int n_in,
                              void* d_out, int out_size, void* d_ws, size_t ws_size,
                              hipStream_t stream) {
  const float* target  = (const float*)d_in[0];  // [32,64,5]
  const float* pcls    = (const float*)d_in[1];  // [32,8400,80]
  const float* pbox    = (const float*)d_in[2];  // [32,8400,4]
  const float* anchors = (const float*)d_in[3];  // [8400,2]
  float* out = (float*)d_out;

  char* ws = (char*)d_ws;
  float*    top_val = (float*)ws;                    // 20480 f  =  81,920 B
  int*      top_idx = (int*)(ws + 81920);            //             81,920 B
  float*    top_iou = (float*)(ws + 163840);         //             81,920 B
  float*    as_tm   = (float*)(ws + 245760);         //             81,920 B
  float*    as_x    = (float*)(ws + 327680);         //             81,920 B
  float*    as_cio  = (float*)(ws + 409600);         //             81,920 B
  int*      as_u    = (int*)(ws + 491520);           //             81,920 B
  unsigned* mtg     = (unsigned*)(ws + 573440);      // 2048 u   =   8,192 B
  unsigned* mig     = (unsigned*)(ws + 581632);      //              8,192 B
  double*   k2_part = (double*)(ws + 589824);        // 96 d     =     768 B
  double*   k3_part = (double*)(ws + 590592);        // 2048 d   =  16,384 B
  // total ws use: 606,976 B

  k_topk<<<NB * NT, 256, 0, stream>>>(target, pcls, pbox,
                                      top_val, top_idx, top_iou, mtg, mig);
  k_resolve<<<(NB * NE * 64) / 256, 256, 0, stream>>>(
      target, pcls, pbox, anchors, top_val, top_idx, top_iou,
      as_tm, as_x, as_cio, as_u, mtg, mig);
  k_bce_sums<<<BCE_BLOCKS + NB, 256, 0, stream>>>(
      pcls, as_tm, as_x, as_cio, as_u, mtg, mig, k3_part, k2_part);
  k_final<<<1, 256, 0, stream>>>(k3_part, k2_part, out);
}